// Round 2
// baseline (1324.514 us; speedup 1.0000x reference)
//
#include <hip/hip_runtime.h>
#include <math.h>

typedef __attribute__((ext_vector_type(8))) short bf16x8;
typedef __attribute__((ext_vector_type(4))) short short4v;
typedef __attribute__((ext_vector_type(4))) float f32x4;

#define SCALE 0.17677669529663687f  // 32^-0.5

__device__ __forceinline__ short f2bf(float f) {
  unsigned u = __builtin_bit_cast(unsigned, f);
  unsigned r = u + 0x7fffu + ((u >> 16) & 1u);
  return (short)(r >> 16);
}

// ---------------- weight casts ----------------
__global__ __launch_bounds__(256) void cast_qkw_kernel(const float* __restrict__ src,
                                                       short* __restrict__ dst) {
  size_t i = (size_t)blockIdx.x * 256 + threadIdx.x;  // groups of 4
  f32x4 v = *(const f32x4*)(src + i * 4);
  float sc = (i * 4 < (size_t)1024 * 1024) ? SCALE : 1.0f;  // q out-rows get scale
  short4v o;
#pragma unroll
  for (int j = 0; j < 4; ++j) o[j] = f2bf(v[j] * sc);
  *(short4v*)(dst + i * 4) = o;
}

__global__ __launch_bounds__(256) void cast_kernel(const float* __restrict__ src,
                                                   short* __restrict__ dst) {
  size_t i = (size_t)blockIdx.x * 256 + threadIdx.x;
  f32x4 v = *(const f32x4*)(src + i * 4);
  short4v o;
#pragma unroll
  for (int j = 0; j < 4; ++j) o[j] = f2bf(v[j]);
  *(short4v*)(dst + i * 4) = o;
}

// ---------------- LN1 + shift + window-partition ----------------
__global__ __launch_bounds__(256) void ln1_permute_kernel(
    const float* __restrict__ x,
    const float* __restrict__ g1, const float* __restrict__ b1,
    short* __restrict__ xnw) {
  int r = blockIdx.x;  // dest row in window order
  int b = r / 3136, rem = r % 3136;
  int wi = rem / 49, n = rem % 49;
  int hs = (wi >> 3) * 7 + n / 7, wsf = (wi & 7) * 7 + n % 7;
  int ho = hs + 3; if (ho >= 56) ho -= 56;
  int wo = wsf + 3; if (wo >= 56) wo -= 56;
  size_t src = ((size_t)b * 3136 + ho * 56 + wo) * 1024;
  int t = threadIdx.x;
  f32x4 xv = *(const f32x4*)(x + src + t * 4);
  float s = xv[0] + xv[1] + xv[2] + xv[3];
  float s2 = xv[0] * xv[0] + xv[1] * xv[1] + xv[2] * xv[2] + xv[3] * xv[3];
#pragma unroll
  for (int m = 1; m < 64; m <<= 1) { s += __shfl_xor(s, m); s2 += __shfl_xor(s2, m); }
  __shared__ float red[8];
  int w = t >> 6;
  if ((t & 63) == 0) { red[w * 2] = s; red[w * 2 + 1] = s2; }
  __syncthreads();
  float ts = red[0] + red[2] + red[4] + red[6];
  float ts2 = red[1] + red[3] + red[5] + red[7];
  float mu = ts * (1.0f / 1024.0f);
  float var = ts2 * (1.0f / 1024.0f) - mu * mu;
  float rs = rsqrtf(var + 1e-5f);
  short4v xo;
#pragma unroll
  for (int j = 0; j < 4; ++j) {
    int cc = t * 4 + j;
    xo[j] = f2bf((xv[j] - mu) * rs * g1[cc] + b1[cc]);
  }
  *(short4v*)(xnw + (size_t)r * 1024 + t * 4) = xo;
}

// ---------------- LN2 ----------------
__global__ __launch_bounds__(256) void ln2_kernel(const float* __restrict__ x2,
                                                  const float* __restrict__ g2,
                                                  const float* __restrict__ b2,
                                                  short* __restrict__ xn2) {
  int r = blockIdx.x;
  size_t src = (size_t)r * 1024;
  int t = threadIdx.x;
  f32x4 xv = *(const f32x4*)(x2 + src + t * 4);
  float s = xv[0] + xv[1] + xv[2] + xv[3];
  float s2 = xv[0] * xv[0] + xv[1] * xv[1] + xv[2] * xv[2] + xv[3] * xv[3];
#pragma unroll
  for (int m = 1; m < 64; m <<= 1) { s += __shfl_xor(s, m); s2 += __shfl_xor(s2, m); }
  __shared__ float red[8];
  int w = t >> 6;
  if ((t & 63) == 0) { red[w * 2] = s; red[w * 2 + 1] = s2; }
  __syncthreads();
  float ts = red[0] + red[2] + red[4] + red[6];
  float ts2 = red[1] + red[3] + red[5] + red[7];
  float mu = ts * (1.0f / 1024.0f);
  float var = ts2 * (1.0f / 1024.0f) - mu * mu;
  float rs = rsqrtf(var + 1e-5f);
  short4v xo;
#pragma unroll
  for (int j = 0; j < 4; ++j) {
    int cc = t * 4 + j;
    xo[j] = f2bf((xv[j] - mu) * rs * g2[cc] + b2[cc]);
  }
  *(short4v*)(xn2 + src + t * 4) = xo;
}

// ---------------- bf16 MFMA GEMM: C[M,N] = A[M,K] @ Bt[N,K]^T, fused epilogues ----------------
// EPI: 0 = qk (bias, pre-scaled, out bf16)  1 = proj (bias + shortcut, scatter to orig order, f32)
//      2 = fc1 (bias + exact gelu, out bf16)  3 = fc2 (bias + residual, out f32; add0 may alias out)
#define LDP 40
template <int EPI>
__global__ __launch_bounds__(256) void gemm_bt(const short* __restrict__ A,
                                               const short* __restrict__ Bt,
                                               const float* __restrict__ bias,
                                               const float* __restrict__ add0,
                                               void* __restrict__ out, int N, int K) {
  __shared__ __align__(16) short As[128 * LDP];
  __shared__ __align__(16) short Bs[128 * LDP];
  int t = threadIdx.x;
  int l = t & 63, w = t >> 6;
  int wm = w >> 1, wn = w & 1;
  int g = l >> 4, c = l & 15;
  const short* Ab = A + (size_t)blockIdx.x * 128 * K;
  const short* Bb = Bt + (size_t)blockIdx.y * 128 * K;
  f32x4 acc[4][4] = {};
  for (int k0 = 0; k0 < K; k0 += 32) {
    __syncthreads();
#pragma unroll
    for (int p = 0; p < 2; ++p) {
      int ch = t + p * 256;            // 512 chunks of 16B
      int row = ch >> 2, col = (ch & 3) * 8;
      *(bf16x8*)&As[row * LDP + col] = *(const bf16x8*)&Ab[(size_t)row * K + k0 + col];
      *(bf16x8*)&Bs[row * LDP + col] = *(const bf16x8*)&Bb[(size_t)row * K + k0 + col];
    }
    __syncthreads();
    bf16x8 af[4], bfr[4];
#pragma unroll
    for (int m = 0; m < 4; ++m) af[m] = *(const bf16x8*)&As[(wm * 64 + m * 16 + c) * LDP + g * 8];
#pragma unroll
    for (int n = 0; n < 4; ++n) bfr[n] = *(const bf16x8*)&Bs[(wn * 64 + n * 16 + c) * LDP + g * 8];
#pragma unroll
    for (int m = 0; m < 4; ++m)
#pragma unroll
      for (int n = 0; n < 4; ++n)
        acc[m][n] = __builtin_amdgcn_mfma_f32_16x16x32_bf16(af[m], bfr[n], acc[m][n], 0, 0, 0);
  }
  int mb = blockIdx.x * 128 + wm * 64;
  int nb = blockIdx.y * 128 + wn * 64;
#pragma unroll
  for (int m = 0; m < 4; ++m) {
#pragma unroll
    for (int i = 0; i < 4; ++i) {
      int row = mb + m * 16 + g * 4 + i;
      size_t orow = row;
      if (EPI == 1) {  // window order -> original order
        int bb = row / 3136, rem = row % 3136;
        int wi = rem / 49, n = rem % 49;
        int hs = (wi >> 3) * 7 + n / 7, wf = (wi & 7) * 7 + n % 7;
        int ho = hs + 3; if (ho >= 56) ho -= 56;
        int wo = wf + 3; if (wo >= 56) wo -= 56;
        orow = (size_t)bb * 3136 + ho * 56 + wo;
      }
#pragma unroll
      for (int n4 = 0; n4 < 4; ++n4) {
        int col = nb + n4 * 16 + c;
        float val = acc[m][n4][i];
        if (EPI == 0) {
          float bv = bias[col] * (col < 1024 ? SCALE : 1.0f);
          ((short*)out)[(size_t)row * N + col] = f2bf(val + bv);
        } else if (EPI == 1) {
          ((float*)out)[orow * 1024 + col] = val + bias[col] + add0[orow * 1024 + col];
        } else if (EPI == 2) {
          float hv = val + bias[col];
          ((short*)out)[(size_t)row * N + col] = f2bf(0.5f * hv * (1.0f + erff(hv * 0.70710678118f)));
        } else {
          float res = add0[(size_t)row * 1024 + col];
          ((float*)out)[(size_t)row * 1024 + col] = val + bias[col] + res;
        }
      }
    }
  }
}

// ---------------- windowed attention: 1 wave = 1 (window, head); V direct from f32 input ----------------
__global__ __launch_bounds__(256) void attn_kernel(const short* __restrict__ qk,
                                                   const float* __restrict__ v,
                                                   const float* __restrict__ rpb,
                                                   short* __restrict__ ao) {
  __shared__ __align__(16) float rpbt[32 * 169];  // [head][idx]
  __shared__ int cnt[49];
  __shared__ __align__(16) short Vt[4][32 * 72];  // [wave][d][j] transposed V, padded
  __shared__ __align__(16) short Pl[4][64 * 72];  // [wave][row][col] P, padded
  int t = threadIdx.x, l = t & 63, w = t >> 6;
  int win = blockIdx.x >> 3;
  int h = (blockIdx.x & 7) * 4 + w;
  // stage bias table transposed
  for (int e = t; e < 169 * 32; e += 256) {
    int hh = e / 169, idx = e - hh * 169;
    rpbt[e] = rpb[idx * 32 + hh];
  }
  if (t < 49) {  // shift-mask region codes for this window
    int wi = win & 63;
    int hs = (wi >> 3) * 7 + t / 7, wsf = (wi & 7) * 7 + t % 7;
    int rh = hs < 49 ? 0 : (hs < 53 ? 1 : 2);
    int rw = wsf < 49 ? 0 : (wsf < 53 ? 1 : 2);
    cnt[t] = rh * 3 + rw;
  }
  // stage V transposed from f32 input with inline roll+window map (zero-pad tokens 49..63)
  if (l < 49) {
    int wi = win & 63, b = win >> 6;
    int hs = (wi >> 3) * 7 + l / 7, wsf = (wi & 7) * 7 + l % 7;
    int ho = hs + 3; if (ho >= 56) ho -= 56;
    int wo = wsf + 3; if (wo >= 56) wo -= 56;
    const float* vp = v + ((size_t)b * 3136 + ho * 56 + wo) * 1024 + h * 32;
#pragma unroll
    for (int d4 = 0; d4 < 8; ++d4) {
      f32x4 vv = *(const f32x4*)(vp + d4 * 4);
#pragma unroll
      for (int j = 0; j < 4; ++j) Vt[w][(d4 * 4 + j) * 72 + l] = f2bf(vv[j]);
    }
  } else {
#pragma unroll
    for (int d = 0; d < 32; ++d) Vt[w][d * 72 + l] = 0;
  }
  __syncthreads();
  int g = l >> 4, c = l & 15;
  // Q/K fragments direct from global (A: row=c, k=g*8+j ; B: col=c, k=g*8+j)
  bf16x8 qf[4], kf[4];
#pragma unroll
  for (int mt = 0; mt < 4; ++mt) {
    int r = mt * 16 + c; if (r > 48) r = 48;
    qf[mt] = *(const bf16x8*)&qk[((size_t)win * 49 + r) * 2048 + h * 32 + g * 8];
  }
#pragma unroll
  for (int nt = 0; nt < 4; ++nt) {
    int j = nt * 16 + c; if (j > 48) j = 48;
    kf[nt] = *(const bf16x8*)&qk[((size_t)win * 49 + j) * 2048 + 1024 + h * 32 + g * 8];
  }
  f32x4 s[4][4] = {};
#pragma unroll
  for (int mt = 0; mt < 4; ++mt)
#pragma unroll
    for (int nt = 0; nt < 4; ++nt)
      s[mt][nt] = __builtin_amdgcn_mfma_f32_16x16x32_bf16(qf[mt], kf[nt], s[mt][nt], 0, 0, 0);
  // bias + mask (+ padding mask)
#pragma unroll
  for (int mt = 0; mt < 4; ++mt)
#pragma unroll
    for (int nt = 0; nt < 4; ++nt)
#pragma unroll
      for (int i = 0; i < 4; ++i) {
        int r = mt * 16 + g * 4 + i;
        int j = nt * 16 + c;
        float val = s[mt][nt][i];
        if (r < 49 && j < 49) {
          int idx = (r / 7 - j / 7 + 6) * 13 + (r % 7 - j % 7 + 6);
          val += rpbt[h * 169 + idx];
          if (cnt[r] != cnt[j]) val -= 100.0f;
        } else {
          val = -1e30f;
        }
        s[mt][nt][i] = val;
      }
  // row softmax: row r's 64 cols live in 4 regs on each of 16 lanes (same g)
#pragma unroll
  for (int mt = 0; mt < 4; ++mt)
#pragma unroll
    for (int i = 0; i < 4; ++i) {
      float mx = s[mt][0][i];
#pragma unroll
      for (int nt = 1; nt < 4; ++nt) mx = fmaxf(mx, s[mt][nt][i]);
#pragma unroll
      for (int m2 = 1; m2 < 16; m2 <<= 1) mx = fmaxf(mx, __shfl_xor(mx, m2));
      float sum = 0.0f;
#pragma unroll
      for (int nt = 0; nt < 4; ++nt) {
        float e = __expf(s[mt][nt][i] - mx);
        s[mt][nt][i] = e;
        sum += e;
      }
#pragma unroll
      for (int m2 = 1; m2 < 16; m2 <<= 1) sum += __shfl_xor(sum, m2);
      float inv = 1.0f / sum;
#pragma unroll
      for (int nt = 0; nt < 4; ++nt) s[mt][nt][i] *= inv;
    }
  // P -> LDS (bf16) to re-fragment for PV
#pragma unroll
  for (int mt = 0; mt < 4; ++mt)
#pragma unroll
    for (int nt = 0; nt < 4; ++nt)
#pragma unroll
      for (int i = 0; i < 4; ++i) {
        int r = mt * 16 + g * 4 + i, j = nt * 16 + c;
        Pl[w][r * 72 + j] = f2bf(s[mt][nt][i]);
      }
  __syncthreads();
  // PV: O[64x32] = P[64x64] @ V[64x32]
  f32x4 o[4][2] = {};
#pragma unroll
  for (int kk = 0; kk < 2; ++kk) {
    bf16x8 vb[2];
#pragma unroll
    for (int n2 = 0; n2 < 2; ++n2)
      vb[n2] = *(const bf16x8*)&Vt[w][(n2 * 16 + c) * 72 + kk * 32 + g * 8];
#pragma unroll
    for (int mt = 0; mt < 4; ++mt) {
      bf16x8 pa = *(const bf16x8*)&Pl[w][(mt * 16 + c) * 72 + kk * 32 + g * 8];
#pragma unroll
      for (int n2 = 0; n2 < 2; ++n2)
        o[mt][n2] = __builtin_amdgcn_mfma_f32_16x16x32_bf16(pa, vb[n2], o[mt][n2], 0, 0, 0);
    }
  }
#pragma unroll
  for (int mt = 0; mt < 4; ++mt)
#pragma unroll
    for (int n2 = 0; n2 < 2; ++n2)
#pragma unroll
      for (int i = 0; i < 4; ++i) {
        int r = mt * 16 + g * 4 + i;
        if (r < 49) {
          int d = n2 * 16 + c;
          ao[((size_t)win * 49 + r) * 1024 + h * 32 + d] = f2bf(o[mt][n2][i]);
        }
      }
}

// ---------------- launch ----------------
extern "C" void kernel_launch(void* const* d_in, const int* in_sizes, int n_in,
                              void* d_out, int out_size, void* d_ws, size_t ws_size,
                              hipStream_t stream) {
  (void)in_sizes; (void)n_in; (void)out_size; (void)ws_size;
  const float* x = (const float*)d_in[0];
  const float* v = (const float*)d_in[1];
  const float* n1g = (const float*)d_in[3];
  const float* n1b = (const float*)d_in[4];
  const float* qkw = (const float*)d_in[5];
  const float* qkb = (const float*)d_in[6];
  const float* rpb = (const float*)d_in[7];
  const float* pjw = (const float*)d_in[8];
  const float* pjb = (const float*)d_in[9];
  const float* n2g = (const float*)d_in[10];
  const float* n2b = (const float*)d_in[11];
  const float* f1w = (const float*)d_in[12];
  const float* f1b = (const float*)d_in[13];
  const float* f2w = (const float*)d_in[14];
  const float* f2b = (const float*)d_in[15];
  char* ws = (char*)d_ws;
  // Peak workspace: 177,209,344 bytes (~169 MiB)
  short* w_qk = (short*)(ws + 0);                    //  4.0 MB
  short* w_pj = (short*)(ws + 4194304);              //  2.0 MB
  short* w_f1 = (short*)(ws + 6291456);              //  8.0 MB
  short* w_f2 = (short*)(ws + 14680064);             //  8.0 MB
  short* xnw  = (short*)(ws + 23068672);             // 50 MB  [ln1 -> qk gemm]
  short* qkbuf= (short*)(ws + 74448896);             // 100 MB [qk gemm -> attn]
  short* aob  = (short*)(ws + 23068672);             // 50 MB  overlays xnw [attn -> proj]
  short* xn2  = (short*)(ws + 23068672);             // 50 MB  overlays aob [ln2 -> fc1]
  short* h1   = (short*)(ws + 74448896);             // 100 MB overlays qkbuf [fc1 -> fc2, per chunk]
  float* out = (float*)d_out;                        // also holds x2 (attn residual)

  cast_qkw_kernel<<<2048, 256, 0, stream>>>(qkw, w_qk);
  cast_kernel<<<1024, 256, 0, stream>>>(pjw, w_pj);
  cast_kernel<<<4096, 256, 0, stream>>>(f1w, w_f1);
  cast_kernel<<<4096, 256, 0, stream>>>(f2w, w_f2);
  ln1_permute_kernel<<<25088, 256, 0, stream>>>(x, n1g, n1b, xnw);
  gemm_bt<0><<<dim3(196, 16), 256, 0, stream>>>(xnw, w_qk, qkb, nullptr, qkbuf, 2048, 1024);
  attn_kernel<<<4096, 256, 0, stream>>>(qkbuf, v, rpb, aob);
  gemm_bt<1><<<dim3(196, 8), 256, 0, stream>>>(aob, w_pj, pjb, x, out, 1024, 1024);
  ln2_kernel<<<25088, 256, 0, stream>>>(out, n2g, n2b, xn2);
  // MLP in 2 M-chunks of 12544 rows (hidden buffer reuses dead qkbuf region)
  for (int ch = 0; ch < 2; ++ch) {
    const short* a1 = xn2 + (size_t)ch * 12544 * 1024;
    float* o2 = out + (size_t)ch * 12544 * 1024;
    gemm_bt<2><<<dim3(98, 32), 256, 0, stream>>>(a1, w_f1, f1b, nullptr, h1, 4096, 1024);
    gemm_bt<3><<<dim3(98, 8), 256, 0, stream>>>(h1, w_f2, f2b, o2, o2, 1024, 4096);
  }
}

// Round 3
// 1317.303 us; speedup vs baseline: 1.0055x; 1.0055x over previous
//
#include <hip/hip_runtime.h>
#include <math.h>

typedef __attribute__((ext_vector_type(8))) short bf16x8;
typedef __attribute__((ext_vector_type(4))) short short4v;
typedef __attribute__((ext_vector_type(4))) float f32x4;

#define SCALE 0.17677669529663687f  // 32^-0.5

__device__ __forceinline__ short f2bf(float f) {
  unsigned u = __builtin_bit_cast(unsigned, f);
  unsigned r = u + 0x7fffu + ((u >> 16) & 1u);
  return (short)(r >> 16);
}

// async global->LDS, 16B per lane (dest must be wave-uniform-base + lane*16)
__device__ __forceinline__ void gll16(const short* g, short* l) {
  __builtin_amdgcn_global_load_lds(
      (const __attribute__((address_space(1))) unsigned int*)g,
      (__attribute__((address_space(3))) unsigned int*)l, 16, 0, 0);
}

// ---------------- weight casts ----------------
__global__ __launch_bounds__(256) void cast_qkw_kernel(const float* __restrict__ src,
                                                       short* __restrict__ dst) {
  size_t i = (size_t)blockIdx.x * 256 + threadIdx.x;  // groups of 4
  f32x4 v = *(const f32x4*)(src + i * 4);
  float sc = (i * 4 < (size_t)1024 * 1024) ? SCALE : 1.0f;  // q out-rows get scale
  short4v o;
#pragma unroll
  for (int j = 0; j < 4; ++j) o[j] = f2bf(v[j] * sc);
  *(short4v*)(dst + i * 4) = o;
}

__global__ __launch_bounds__(256) void cast_kernel(const float* __restrict__ src,
                                                   short* __restrict__ dst) {
  size_t i = (size_t)blockIdx.x * 256 + threadIdx.x;
  f32x4 v = *(const f32x4*)(src + i * 4);
  short4v o;
#pragma unroll
  for (int j = 0; j < 4; ++j) o[j] = f2bf(v[j]);
  *(short4v*)(dst + i * 4) = o;
}

// ---------------- LN1 + shift + window-partition ----------------
__global__ __launch_bounds__(256) void ln1_permute_kernel(
    const float* __restrict__ x,
    const float* __restrict__ g1, const float* __restrict__ b1,
    short* __restrict__ xnw) {
  int r = blockIdx.x;  // dest row in window order
  int b = r / 3136, rem = r % 3136;
  int wi = rem / 49, n = rem % 49;
  int hs = (wi >> 3) * 7 + n / 7, wsf = (wi & 7) * 7 + n % 7;
  int ho = hs + 3; if (ho >= 56) ho -= 56;
  int wo = wsf + 3; if (wo >= 56) wo -= 56;
  size_t src = ((size_t)b * 3136 + ho * 56 + wo) * 1024;
  int t = threadIdx.x;
  f32x4 xv = *(const f32x4*)(x + src + t * 4);
  float s = xv[0] + xv[1] + xv[2] + xv[3];
  float s2 = xv[0] * xv[0] + xv[1] * xv[1] + xv[2] * xv[2] + xv[3] * xv[3];
#pragma unroll
  for (int m = 1; m < 64; m <<= 1) { s += __shfl_xor(s, m); s2 += __shfl_xor(s2, m); }
  __shared__ float red[8];
  int w = t >> 6;
  if ((t & 63) == 0) { red[w * 2] = s; red[w * 2 + 1] = s2; }
  __syncthreads();
  float ts = red[0] + red[2] + red[4] + red[6];
  float ts2 = red[1] + red[3] + red[5] + red[7];
  float mu = ts * (1.0f / 1024.0f);
  float var = ts2 * (1.0f / 1024.0f) - mu * mu;
  float rs = rsqrtf(var + 1e-5f);
  short4v xo;
#pragma unroll
  for (int j = 0; j < 4; ++j) {
    int cc = t * 4 + j;
    xo[j] = f2bf((xv[j] - mu) * rs * g1[cc] + b1[cc]);
  }
  *(short4v*)(xnw + (size_t)r * 1024 + t * 4) = xo;
}

// ---------------- LN2 ----------------
__global__ __launch_bounds__(256) void ln2_kernel(const float* __restrict__ x2,
                                                  const float* __restrict__ g2,
                                                  const float* __restrict__ b2,
                                                  short* __restrict__ xn2) {
  int r = blockIdx.x;
  size_t src = (size_t)r * 1024;
  int t = threadIdx.x;
  f32x4 xv = *(const f32x4*)(x2 + src + t * 4);
  float s = xv[0] + xv[1] + xv[2] + xv[3];
  float s2 = xv[0] * xv[0] + xv[1] * xv[1] + xv[2] * xv[2] + xv[3] * xv[3];
#pragma unroll
  for (int m = 1; m < 64; m <<= 1) { s += __shfl_xor(s, m); s2 += __shfl_xor(s2, m); }
  __shared__ float red[8];
  int w = t >> 6;
  if ((t & 63) == 0) { red[w * 2] = s; red[w * 2 + 1] = s2; }
  __syncthreads();
  float ts = red[0] + red[2] + red[4] + red[6];
  float ts2 = red[1] + red[3] + red[5] + red[7];
  float mu = ts * (1.0f / 1024.0f);
  float var = ts2 * (1.0f / 1024.0f) - mu * mu;
  float rs = rsqrtf(var + 1e-5f);
  short4v xo;
#pragma unroll
  for (int j = 0; j < 4; ++j) {
    int cc = t * 4 + j;
    xo[j] = f2bf((xv[j] - mu) * rs * g2[cc] + b2[cc]);
  }
  *(short4v*)(xn2 + src + t * 4) = xo;
}

// ---------------- bf16 MFMA GEMM (m97 structure): C[M,N] = A[M,K] @ Bt[N,K]^T ----------------
// 128x128 tile, BK=32, linear LDS, global_load_lds width-16 staging, 2 barriers/K-step,
// XCD-chunked block swizzle (grids all have nwg % 8 == 0).
// EPI: 0 = qk (bias, pre-scaled, out bf16)  1 = proj (bias + shortcut, scatter to orig order, f32)
//      2 = fc1 (bias + exact gelu, out bf16)  3 = fc2 (bias + residual, out f32; add0 may alias out)
template <int EPI>
__global__ __launch_bounds__(256) void gemm_bt(const short* __restrict__ A,
                                               const short* __restrict__ Bt,
                                               const float* __restrict__ bias,
                                               const float* __restrict__ add0,
                                               void* __restrict__ out, int N, int K) {
  __shared__ __align__(16) short As[128 * 32];
  __shared__ __align__(16) short Bs[128 * 32];
  int t = threadIdx.x;
  int l = t & 63, w = t >> 6;
  int wm = w >> 1, wn = w & 1;
  int g = l >> 4, c = l & 15;
  // XCD-aware chunked swizzle (bijective since nwg % 8 == 0)
  int nwg = gridDim.x * gridDim.y;
  int bid = blockIdx.x + blockIdx.y * gridDim.x;
  int cpx = nwg >> 3;
  int swz = (bid & 7) * cpx + (bid >> 3);
  int bx = swz % gridDim.x, by = swz / gridDim.x;
  const short* Ab = A + (size_t)bx * 128 * K;
  const short* Bb = Bt + (size_t)by * 128 * K;
  // staging map: 256 lanes x 16B = 4KB = 64 rows x 32 bf16; lane t -> row t>>2, col (t&3)*8.
  // LDS dest offset == linear lane*16 within each wave => valid for global_load_lds.
  int srow = t >> 2, scol = (t & 3) * 8;
  const short* gA = Ab + (size_t)srow * K + scol;
  const short* gB = Bb + (size_t)srow * K + scol;
  short* lA = As + srow * 32 + scol;
  short* lB = Bs + srow * 32 + scol;
  f32x4 acc[4][4] = {};
  for (int k0 = 0; k0 < K; k0 += 32) {
    gll16(gA + k0, lA);
    gll16(gA + (size_t)64 * K + k0, lA + 64 * 32);
    gll16(gB + k0, lB);
    gll16(gB + (size_t)64 * K + k0, lB + 64 * 32);
    __syncthreads();  // drains vmcnt -> staged data visible
    bf16x8 af[4], bfr[4];
#pragma unroll
    for (int m = 0; m < 4; ++m) af[m] = *(const bf16x8*)&As[(wm * 64 + m * 16 + c) * 32 + g * 8];
#pragma unroll
    for (int n = 0; n < 4; ++n) bfr[n] = *(const bf16x8*)&Bs[(wn * 64 + n * 16 + c) * 32 + g * 8];
#pragma unroll
    for (int m = 0; m < 4; ++m)
#pragma unroll
      for (int n = 0; n < 4; ++n)
        acc[m][n] = __builtin_amdgcn_mfma_f32_16x16x32_bf16(af[m], bfr[n], acc[m][n], 0, 0, 0);
    __syncthreads();  // readers done before next stage overwrites
  }
  int mb = bx * 128 + wm * 64;
  int nb = by * 128 + wn * 64;
#pragma unroll
  for (int m = 0; m < 4; ++m) {
#pragma unroll
    for (int i = 0; i < 4; ++i) {
      int row = mb + m * 16 + g * 4 + i;
      size_t orow = row;
      if (EPI == 1) {  // window order -> original order
        int bb = row / 3136, rem = row % 3136;
        int wi = rem / 49, n = rem % 49;
        int hs = (wi >> 3) * 7 + n / 7, wf = (wi & 7) * 7 + n % 7;
        int ho = hs + 3; if (ho >= 56) ho -= 56;
        int wo = wf + 3; if (wo >= 56) wo -= 56;
        orow = (size_t)bb * 3136 + ho * 56 + wo;
      }
#pragma unroll
      for (int n4 = 0; n4 < 4; ++n4) {
        int col = nb + n4 * 16 + c;
        float val = acc[m][n4][i];
        if (EPI == 0) {
          float bv = bias[col] * (col < 1024 ? SCALE : 1.0f);
          ((short*)out)[(size_t)row * N + col] = f2bf(val + bv);
        } else if (EPI == 1) {
          ((float*)out)[orow * 1024 + col] = val + bias[col] + add0[orow * 1024 + col];
        } else if (EPI == 2) {
          float hv = val + bias[col];
          ((short*)out)[(size_t)row * N + col] = f2bf(0.5f * hv * (1.0f + erff(hv * 0.70710678118f)));
        } else {
          float res = add0[(size_t)row * 1024 + col];
          ((float*)out)[(size_t)row * 1024 + col] = val + bias[col] + res;
        }
      }
    }
  }
}

// ---------------- windowed attention: 1 wave = 1 (window, head); V direct from f32 input ----------------
__global__ __launch_bounds__(256) void attn_kernel(const short* __restrict__ qk,
                                                   const float* __restrict__ v,
                                                   const float* __restrict__ rpb,
                                                   short* __restrict__ ao) {
  __shared__ __align__(16) float rpbt[32 * 169];  // [head][idx]
  __shared__ int cnt[49];
  __shared__ __align__(16) short Vt[4][32 * 72];  // [wave][d][j] transposed V, padded
  __shared__ __align__(16) short Pl[4][64 * 72];  // [wave][row][col] P, padded
  int t = threadIdx.x, l = t & 63, w = t >> 6;
  int win = blockIdx.x >> 3;
  int h = (blockIdx.x & 7) * 4 + w;
  // stage bias table transposed
  for (int e = t; e < 169 * 32; e += 256) {
    int hh = e / 169, idx = e - hh * 169;
    rpbt[e] = rpb[idx * 32 + hh];
  }
  if (t < 49) {  // shift-mask region codes for this window
    int wi = win & 63;
    int hs = (wi >> 3) * 7 + t / 7, wsf = (wi & 7) * 7 + t % 7;
    int rh = hs < 49 ? 0 : (hs < 53 ? 1 : 2);
    int rw = wsf < 49 ? 0 : (wsf < 53 ? 1 : 2);
    cnt[t] = rh * 3 + rw;
  }
  // stage V transposed from f32 input with inline roll+window map (zero-pad tokens 49..63)
  if (l < 49) {
    int wi = win & 63, b = win >> 6;
    int hs = (wi >> 3) * 7 + l / 7, wsf = (wi & 7) * 7 + l % 7;
    int ho = hs + 3; if (ho >= 56) ho -= 56;
    int wo = wsf + 3; if (wo >= 56) wo -= 56;
    const float* vp = v + ((size_t)b * 3136 + ho * 56 + wo) * 1024 + h * 32;
#pragma unroll
    for (int d4 = 0; d4 < 8; ++d4) {
      f32x4 vv = *(const f32x4*)(vp + d4 * 4);
#pragma unroll
      for (int j = 0; j < 4; ++j) Vt[w][(d4 * 4 + j) * 72 + l] = f2bf(vv[j]);
    }
  } else {
#pragma unroll
    for (int d = 0; d < 32; ++d) Vt[w][d * 72 + l] = 0;
  }
  __syncthreads();
  int g = l >> 4, c = l & 15;
  // Q/K fragments direct from global (A: row=c, k=g*8+j ; B: col=c, k=g*8+j)
  bf16x8 qf[4], kf[4];
#pragma unroll
  for (int mt = 0; mt < 4; ++mt) {
    int r = mt * 16 + c; if (r > 48) r = 48;
    qf[mt] = *(const bf16x8*)&qk[((size_t)win * 49 + r) * 2048 + h * 32 + g * 8];
  }
#pragma unroll
  for (int nt = 0; nt < 4; ++nt) {
    int j = nt * 16 + c; if (j > 48) j = 48;
    kf[nt] = *(const bf16x8*)&qk[((size_t)win * 49 + j) * 2048 + 1024 + h * 32 + g * 8];
  }
  f32x4 s[4][4] = {};
#pragma unroll
  for (int mt = 0; mt < 4; ++mt)
#pragma unroll
    for (int nt = 0; nt < 4; ++nt)
      s[mt][nt] = __builtin_amdgcn_mfma_f32_16x16x32_bf16(qf[mt], kf[nt], s[mt][nt], 0, 0, 0);
  // bias + mask (+ padding mask)
#pragma unroll
  for (int mt = 0; mt < 4; ++mt)
#pragma unroll
    for (int nt = 0; nt < 4; ++nt)
#pragma unroll
      for (int i = 0; i < 4; ++i) {
        int r = mt * 16 + g * 4 + i;
        int j = nt * 16 + c;
        float val = s[mt][nt][i];
        if (r < 49 && j < 49) {
          int idx = (r / 7 - j / 7 + 6) * 13 + (r % 7 - j % 7 + 6);
          val += rpbt[h * 169 + idx];
          if (cnt[r] != cnt[j]) val -= 100.0f;
        } else {
          val = -1e30f;
        }
        s[mt][nt][i] = val;
      }
  // row softmax: row r's 64 cols live in 4 regs on each of 16 lanes (same g)
#pragma unroll
  for (int mt = 0; mt < 4; ++mt)
#pragma unroll
    for (int i = 0; i < 4; ++i) {
      float mx = s[mt][0][i];
#pragma unroll
      for (int nt = 1; nt < 4; ++nt) mx = fmaxf(mx, s[mt][nt][i]);
#pragma unroll
      for (int m2 = 1; m2 < 16; m2 <<= 1) mx = fmaxf(mx, __shfl_xor(mx, m2));
      float sum = 0.0f;
#pragma unroll
      for (int nt = 0; nt < 4; ++nt) {
        float e = __expf(s[mt][nt][i] - mx);
        s[mt][nt][i] = e;
        sum += e;
      }
#pragma unroll
      for (int m2 = 1; m2 < 16; m2 <<= 1) sum += __shfl_xor(sum, m2);
      float inv = 1.0f / sum;
#pragma unroll
      for (int nt = 0; nt < 4; ++nt) s[mt][nt][i] *= inv;
    }
  // P -> LDS (bf16) to re-fragment for PV
#pragma unroll
  for (int mt = 0; mt < 4; ++mt)
#pragma unroll
    for (int nt = 0; nt < 4; ++nt)
#pragma unroll
      for (int i = 0; i < 4; ++i) {
        int r = mt * 16 + g * 4 + i, j = nt * 16 + c;
        Pl[w][r * 72 + j] = f2bf(s[mt][nt][i]);
      }
  __syncthreads();
  // PV: O[64x32] = P[64x64] @ V[64x32]
  f32x4 o[4][2] = {};
#pragma unroll
  for (int kk = 0; kk < 2; ++kk) {
    bf16x8 vb[2];
#pragma unroll
    for (int n2 = 0; n2 < 2; ++n2)
      vb[n2] = *(const bf16x8*)&Vt[w][(n2 * 16 + c) * 72 + kk * 32 + g * 8];
#pragma unroll
    for (int mt = 0; mt < 4; ++mt) {
      bf16x8 pa = *(const bf16x8*)&Pl[w][(mt * 16 + c) * 72 + kk * 32 + g * 8];
#pragma unroll
      for (int n2 = 0; n2 < 2; ++n2)
        o[mt][n2] = __builtin_amdgcn_mfma_f32_16x16x32_bf16(pa, vb[n2], o[mt][n2], 0, 0, 0);
    }
  }
#pragma unroll
  for (int mt = 0; mt < 4; ++mt)
#pragma unroll
    for (int n2 = 0; n2 < 2; ++n2)
#pragma unroll
      for (int i = 0; i < 4; ++i) {
        int r = mt * 16 + g * 4 + i;
        if (r < 49) {
          int d = n2 * 16 + c;
          ao[((size_t)win * 49 + r) * 1024 + h * 32 + d] = f2bf(o[mt][n2][i]);
        }
      }
}

// ---------------- launch ----------------
extern "C" void kernel_launch(void* const* d_in, const int* in_sizes, int n_in,
                              void* d_out, int out_size, void* d_ws, size_t ws_size,
                              hipStream_t stream) {
  (void)in_sizes; (void)n_in; (void)out_size; (void)ws_size;
  const float* x = (const float*)d_in[0];
  const float* v = (const float*)d_in[1];
  const float* n1g = (const float*)d_in[3];
  const float* n1b = (const float*)d_in[4];
  const float* qkw = (const float*)d_in[5];
  const float* qkb = (const float*)d_in[6];
  const float* rpb = (const float*)d_in[7];
  const float* pjw = (const float*)d_in[8];
  const float* pjb = (const float*)d_in[9];
  const float* n2g = (const float*)d_in[10];
  const float* n2b = (const float*)d_in[11];
  const float* f1w = (const float*)d_in[12];
  const float* f1b = (const float*)d_in[13];
  const float* f2w = (const float*)d_in[14];
  const float* f2b = (const float*)d_in[15];
  char* ws = (char*)d_ws;
  // Peak workspace: ~169 MiB
  short* w_qk = (short*)(ws + 0);                    //  4.0 MB
  short* w_pj = (short*)(ws + 4194304);              //  2.0 MB
  short* w_f1 = (short*)(ws + 6291456);              //  8.0 MB
  short* w_f2 = (short*)(ws + 14680064);             //  8.0 MB
  short* xnw  = (short*)(ws + 23068672);             // 50 MB  [ln1 -> qk gemm]
  short* qkbuf= (short*)(ws + 74448896);             // 100 MB [qk gemm -> attn]
  short* aob  = (short*)(ws + 23068672);             // 50 MB  overlays xnw [attn -> proj]
  short* xn2  = (short*)(ws + 23068672);             // 50 MB  overlays aob [ln2 -> fc1]
  short* h1   = (short*)(ws + 74448896);             // 100 MB overlays qkbuf [fc1 -> fc2, per chunk]
  float* out = (float*)d_out;                        // also holds x2 (attn residual)

  cast_qkw_kernel<<<2048, 256, 0, stream>>>(qkw, w_qk);
  cast_kernel<<<1024, 256, 0, stream>>>(pjw, w_pj);
  cast_kernel<<<4096, 256, 0, stream>>>(f1w, w_f1);
  cast_kernel<<<4096, 256, 0, stream>>>(f2w, w_f2);
  ln1_permute_kernel<<<25088, 256, 0, stream>>>(x, n1g, n1b, xnw);
  gemm_bt<0><<<dim3(196, 16), 256, 0, stream>>>(xnw, w_qk, qkb, nullptr, qkbuf, 2048, 1024);
  attn_kernel<<<4096, 256, 0, stream>>>(qkbuf, v, rpb, aob);
  gemm_bt<1><<<dim3(196, 8), 256, 0, stream>>>(aob, w_pj, pjb, x, out, 1024, 1024);
  ln2_kernel<<<25088, 256, 0, stream>>>(out, n2g, n2b, xn2);
  // MLP in 2 M-chunks of 12544 rows (hidden buffer reuses dead qkbuf region)
  for (int ch = 0; ch < 2; ++ch) {
    const short* a1 = xn2 + (size_t)ch * 12544 * 1024;
    float* o2 = out + (size_t)ch * 12544 * 1024;
    gemm_bt<2><<<dim3(98, 32), 256, 0, stream>>>(a1, w_f1, f1b, nullptr, h1, 4096, 1024);
    gemm_bt<3><<<dim3(98, 8), 256, 0, stream>>>(h1, w_f2, f2b, o2, o2, 1024, 4096);
  }
}

// Round 4
// 1257.362 us; speedup vs baseline: 1.0534x; 1.0477x over previous
//
#include <hip/hip_runtime.h>
#include <math.h>

typedef __attribute__((ext_vector_type(8))) short bf16x8;
typedef __attribute__((ext_vector_type(4))) short short4v;
typedef __attribute__((ext_vector_type(4))) float f32x4;

#define SCALE 0.17677669529663687f  // 32^-0.5

__device__ __forceinline__ short f2bf(float f) {
  unsigned u = __builtin_bit_cast(unsigned, f);
  unsigned r = u + 0x7fffu + ((u >> 16) & 1u);
  return (short)(r >> 16);
}

// async global->LDS, 16B per lane (dest = wave-uniform base + lane*16; our t*16B layout satisfies it)
__device__ __forceinline__ void gll16(const short* g, short* l) {
  __builtin_amdgcn_global_load_lds(
      (const __attribute__((address_space(1))) unsigned int*)g,
      (__attribute__((address_space(3))) unsigned int*)l, 16, 0, 0);
}

// ---------------- weight casts ----------------
__global__ __launch_bounds__(256) void cast_qkw_kernel(const float* __restrict__ src,
                                                       short* __restrict__ dst) {
  size_t i = (size_t)blockIdx.x * 256 + threadIdx.x;  // groups of 4
  f32x4 v = *(const f32x4*)(src + i * 4);
  float sc = (i * 4 < (size_t)1024 * 1024) ? SCALE : 1.0f;  // q out-rows get scale
  short4v o;
#pragma unroll
  for (int j = 0; j < 4; ++j) o[j] = f2bf(v[j] * sc);
  *(short4v*)(dst + i * 4) = o;
}

__global__ __launch_bounds__(256) void cast_kernel(const float* __restrict__ src,
                                                   short* __restrict__ dst) {
  size_t i = (size_t)blockIdx.x * 256 + threadIdx.x;
  f32x4 v = *(const f32x4*)(src + i * 4);
  short4v o;
#pragma unroll
  for (int j = 0; j < 4; ++j) o[j] = f2bf(v[j]);
  *(short4v*)(dst + i * 4) = o;
}

// ---------------- LN1 + shift + window-partition ----------------
__global__ __launch_bounds__(256) void ln1_permute_kernel(
    const float* __restrict__ x,
    const float* __restrict__ g1, const float* __restrict__ b1,
    short* __restrict__ xnw) {
  int r = blockIdx.x;  // dest row in window order
  int b = r / 3136, rem = r % 3136;
  int wi = rem / 49, n = rem % 49;
  int hs = (wi >> 3) * 7 + n / 7, wsf = (wi & 7) * 7 + n % 7;
  int ho = hs + 3; if (ho >= 56) ho -= 56;
  int wo = wsf + 3; if (wo >= 56) wo -= 56;
  size_t src = ((size_t)b * 3136 + ho * 56 + wo) * 1024;
  int t = threadIdx.x;
  f32x4 xv = *(const f32x4*)(x + src + t * 4);
  float s = xv[0] + xv[1] + xv[2] + xv[3];
  float s2 = xv[0] * xv[0] + xv[1] * xv[1] + xv[2] * xv[2] + xv[3] * xv[3];
#pragma unroll
  for (int m = 1; m < 64; m <<= 1) { s += __shfl_xor(s, m); s2 += __shfl_xor(s2, m); }
  __shared__ float red[8];
  int w = t >> 6;
  if ((t & 63) == 0) { red[w * 2] = s; red[w * 2 + 1] = s2; }
  __syncthreads();
  float ts = red[0] + red[2] + red[4] + red[6];
  float ts2 = red[1] + red[3] + red[5] + red[7];
  float mu = ts * (1.0f / 1024.0f);
  float var = ts2 * (1.0f / 1024.0f) - mu * mu;
  float rs = rsqrtf(var + 1e-5f);
  short4v xo;
#pragma unroll
  for (int j = 0; j < 4; ++j) {
    int cc = t * 4 + j;
    xo[j] = f2bf((xv[j] - mu) * rs * g1[cc] + b1[cc]);
  }
  *(short4v*)(xnw + (size_t)r * 1024 + t * 4) = xo;
}

// ---------------- LN2 ----------------
__global__ __launch_bounds__(256) void ln2_kernel(const float* __restrict__ x2,
                                                  const float* __restrict__ g2,
                                                  const float* __restrict__ b2,
                                                  short* __restrict__ xn2) {
  int r = blockIdx.x;
  size_t src = (size_t)r * 1024;
  int t = threadIdx.x;
  f32x4 xv = *(const f32x4*)(x2 + src + t * 4);
  float s = xv[0] + xv[1] + xv[2] + xv[3];
  float s2 = xv[0] * xv[0] + xv[1] * xv[1] + xv[2] * xv[2] + xv[3] * xv[3];
#pragma unroll
  for (int m = 1; m < 64; m <<= 1) { s += __shfl_xor(s, m); s2 += __shfl_xor(s2, m); }
  __shared__ float red[8];
  int w = t >> 6;
  if ((t & 63) == 0) { red[w * 2] = s; red[w * 2 + 1] = s2; }
  __syncthreads();
  float ts = red[0] + red[2] + red[4] + red[6];
  float ts2 = red[1] + red[3] + red[5] + red[7];
  float mu = ts * (1.0f / 1024.0f);
  float var = ts2 * (1.0f / 1024.0f) - mu * mu;
  float rs = rsqrtf(var + 1e-5f);
  short4v xo;
#pragma unroll
  for (int j = 0; j < 4; ++j) {
    int cc = t * 4 + j;
    xo[j] = f2bf((xv[j] - mu) * rs * g2[cc] + b2[cc]);
  }
  *(short4v*)(xn2 + src + t * 4) = xo;
}

// ---------------- bf16 MFMA GEMM, depth-2 async prefetch (T3/T4/T5) ----------------
// C[M,N] = A[M,K] @ Bt[N,K]^T. 128x128 tile, BK=32, 3-deep LDS ring (48KB),
// counted s_waitcnt vmcnt(4) + raw s_barrier (loads stay in flight across barriers).
// EPI: 0 = qk (bias, pre-scaled, out bf16)  1 = proj (bias + shortcut, scatter to orig order, f32)
//      2 = fc1 (bias + exact gelu, out bf16)  3 = fc2 (bias + residual, out f32; add0 may alias out)
template <int EPI>
__global__ __launch_bounds__(256) void gemm_bt(const short* __restrict__ A,
                                               const short* __restrict__ Bt,
                                               const float* __restrict__ bias,
                                               const float* __restrict__ add0,
                                               void* __restrict__ out, int N, int K) {
  __shared__ __align__(16) short As[3][64 * 64];  // 3 x 8KB (128 rows x 32 cols)
  __shared__ __align__(16) short Bs[3][64 * 64];
  int t = threadIdx.x;
  int l = t & 63, w = t >> 6;
  int wm = w >> 1, wn = w & 1;
  int g = l >> 4, c = l & 15;
  // XCD-aware chunked swizzle (bijective since nwg % 8 == 0)
  int nwg = gridDim.x * gridDim.y;
  int bid = blockIdx.x + blockIdx.y * gridDim.x;
  int cpx = nwg >> 3;
  int swz = (bid & 7) * cpx + (bid >> 3);
  int bx = swz % gridDim.x, by = swz / gridDim.x;
  const short* Ab = A + (size_t)bx * 128 * K;
  const short* Bb = Bt + (size_t)by * 128 * K;
  // staging map: lane t -> row t>>2, col (t&3)*8 ; LDS offset = t*16B (linear per wave)
  int srow = t >> 2, scol = (t & 3) * 8;
  const short* gA = Ab + (size_t)srow * K + scol;
  const short* gB = Bb + (size_t)srow * K + scol;
  int NT = K >> 5;

#define STAGE(bb, tt)                                          \
  do {                                                         \
    int k0 = (tt) << 5;                                        \
    gll16(gA + k0, &As[bb][t * 8]);                            \
    gll16(gA + (size_t)64 * K + k0, &As[bb][2048 + t * 8]);    \
    gll16(gB + k0, &Bs[bb][t * 8]);                            \
    gll16(gB + (size_t)64 * K + k0, &Bs[bb][2048 + t * 8]);    \
  } while (0)

  f32x4 acc[4][4] = {};
  STAGE(0, 0);
  STAGE(1, 1);
  asm volatile("s_waitcnt vmcnt(4)" ::: "memory");  // tile 0 landed; tile 1 in flight
  __builtin_amdgcn_sched_barrier(0);
  __builtin_amdgcn_s_barrier();
  __builtin_amdgcn_sched_barrier(0);
  for (int tt = 0; tt < NT; ++tt) {
    int cur = tt % 3;
    if (tt + 2 < NT) STAGE((tt + 2) % 3, tt + 2);  // lands into buffer last read at iter tt-1
    bf16x8 af[4], bfr[4];
#pragma unroll
    for (int m = 0; m < 4; ++m) af[m] = *(const bf16x8*)&As[cur][(wm * 64 + m * 16 + c) * 32 + g * 8];
#pragma unroll
    for (int n = 0; n < 4; ++n) bfr[n] = *(const bf16x8*)&Bs[cur][(wn * 64 + n * 16 + c) * 32 + g * 8];
    __builtin_amdgcn_s_setprio(1);
#pragma unroll
    for (int m = 0; m < 4; ++m)
#pragma unroll
      for (int n = 0; n < 4; ++n)
        acc[m][n] = __builtin_amdgcn_mfma_f32_16x16x32_bf16(af[m], bfr[n], acc[m][n], 0, 0, 0);
    __builtin_amdgcn_s_setprio(0);
    // counted wait: next tile landed, tile after stays in flight (never vmcnt(0) mid-loop)
    if (tt + 2 < NT) {
      asm volatile("s_waitcnt vmcnt(4)" ::: "memory");
    } else if (tt + 1 < NT) {
      asm volatile("s_waitcnt vmcnt(0)" ::: "memory");
    }
    __builtin_amdgcn_sched_barrier(0);
    __builtin_amdgcn_s_barrier();
    __builtin_amdgcn_sched_barrier(0);
  }
#undef STAGE
  int mb = bx * 128 + wm * 64;
  int nb = by * 128 + wn * 64;
#pragma unroll
  for (int m = 0; m < 4; ++m) {
#pragma unroll
    for (int i = 0; i < 4; ++i) {
      int row = mb + m * 16 + g * 4 + i;
      size_t orow = row;
      if (EPI == 1) {  // window order -> original order
        int bb = row / 3136, rem = row % 3136;
        int wi = rem / 49, n = rem % 49;
        int hs = (wi >> 3) * 7 + n / 7, wf = (wi & 7) * 7 + n % 7;
        int ho = hs + 3; if (ho >= 56) ho -= 56;
        int wo = wf + 3; if (wo >= 56) wo -= 56;
        orow = (size_t)bb * 3136 + ho * 56 + wo;
      }
#pragma unroll
      for (int n4 = 0; n4 < 4; ++n4) {
        int col = nb + n4 * 16 + c;
        float val = acc[m][n4][i];
        if (EPI == 0) {
          float bv = bias[col] * (col < 1024 ? SCALE : 1.0f);
          ((short*)out)[(size_t)row * N + col] = f2bf(val + bv);
        } else if (EPI == 1) {
          ((float*)out)[orow * 1024 + col] = val + bias[col] + add0[orow * 1024 + col];
        } else if (EPI == 2) {
          float hv = val + bias[col];
          ((short*)out)[(size_t)row * N + col] = f2bf(0.5f * hv * (1.0f + erff(hv * 0.70710678118f)));
        } else {
          float res = add0[(size_t)row * 1024 + col];
          ((float*)out)[(size_t)row * 1024 + col] = val + bias[col] + res;
        }
      }
    }
  }
}

// ---------------- windowed attention: 1 wave = 1 (window, head); V direct from f32 input ----------------
__global__ __launch_bounds__(256) void attn_kernel(const short* __restrict__ qk,
                                                   const float* __restrict__ v,
                                                   const float* __restrict__ rpb,
                                                   short* __restrict__ ao) {
  __shared__ __align__(16) float rpbt[32 * 169];  // [head][idx]
  __shared__ int cnt[49];
  __shared__ __align__(16) short Vt[4][32 * 72];  // [wave][d][j] transposed V, padded
  __shared__ __align__(16) short Pl[4][64 * 72];  // [wave][row][col] P, padded
  int t = threadIdx.x, l = t & 63, w = t >> 6;
  int win = blockIdx.x >> 3;
  int h = (blockIdx.x & 7) * 4 + w;
  // stage bias table transposed
  for (int e = t; e < 169 * 32; e += 256) {
    int hh = e / 169, idx = e - hh * 169;
    rpbt[e] = rpb[idx * 32 + hh];
  }
  if (t < 49) {  // shift-mask region codes for this window
    int wi = win & 63;
    int hs = (wi >> 3) * 7 + t / 7, wsf = (wi & 7) * 7 + t % 7;
    int rh = hs < 49 ? 0 : (hs < 53 ? 1 : 2);
    int rw = wsf < 49 ? 0 : (wsf < 53 ? 1 : 2);
    cnt[t] = rh * 3 + rw;
  }
  // stage V transposed from f32 input with inline roll+window map (zero-pad tokens 49..63)
  if (l < 49) {
    int wi = win & 63, b = win >> 6;
    int hs = (wi >> 3) * 7 + l / 7, wsf = (wi & 7) * 7 + l % 7;
    int ho = hs + 3; if (ho >= 56) ho -= 56;
    int wo = wsf + 3; if (wo >= 56) wo -= 56;
    const float* vp = v + ((size_t)b * 3136 + ho * 56 + wo) * 1024 + h * 32;
#pragma unroll
    for (int d4 = 0; d4 < 8; ++d4) {
      f32x4 vv = *(const f32x4*)(vp + d4 * 4);
#pragma unroll
      for (int j = 0; j < 4; ++j) Vt[w][(d4 * 4 + j) * 72 + l] = f2bf(vv[j]);
    }
  } else {
#pragma unroll
    for (int d = 0; d < 32; ++d) Vt[w][d * 72 + l] = 0;
  }
  __syncthreads();
  int g = l >> 4, c = l & 15;
  // Q/K fragments direct from global (A: row=c, k=g*8+j ; B: col=c, k=g*8+j)
  bf16x8 qf[4], kf[4];
#pragma unroll
  for (int mt = 0; mt < 4; ++mt) {
    int r = mt * 16 + c; if (r > 48) r = 48;
    qf[mt] = *(const bf16x8*)&qk[((size_t)win * 49 + r) * 2048 + h * 32 + g * 8];
  }
#pragma unroll
  for (int nt = 0; nt < 4; ++nt) {
    int j = nt * 16 + c; if (j > 48) j = 48;
    kf[nt] = *(const bf16x8*)&qk[((size_t)win * 49 + j) * 2048 + 1024 + h * 32 + g * 8];
  }
  f32x4 s[4][4] = {};
#pragma unroll
  for (int mt = 0; mt < 4; ++mt)
#pragma unroll
    for (int nt = 0; nt < 4; ++nt)
      s[mt][nt] = __builtin_amdgcn_mfma_f32_16x16x32_bf16(qf[mt], kf[nt], s[mt][nt], 0, 0, 0);
  // bias + mask (+ padding mask)
#pragma unroll
  for (int mt = 0; mt < 4; ++mt)
#pragma unroll
    for (int nt = 0; nt < 4; ++nt)
#pragma unroll
      for (int i = 0; i < 4; ++i) {
        int r = mt * 16 + g * 4 + i;
        int j = nt * 16 + c;
        float val = s[mt][nt][i];
        if (r < 49 && j < 49) {
          int idx = (r / 7 - j / 7 + 6) * 13 + (r % 7 - j % 7 + 6);
          val += rpbt[h * 169 + idx];
          if (cnt[r] != cnt[j]) val -= 100.0f;
        } else {
          val = -1e30f;
        }
        s[mt][nt][i] = val;
      }
  // row softmax: row r's 64 cols live in 4 regs on each of 16 lanes (same g)
#pragma unroll
  for (int mt = 0; mt < 4; ++mt)
#pragma unroll
    for (int i = 0; i < 4; ++i) {
      float mx = s[mt][0][i];
#pragma unroll
      for (int nt = 1; nt < 4; ++nt) mx = fmaxf(mx, s[mt][nt][i]);
#pragma unroll
      for (int m2 = 1; m2 < 16; m2 <<= 1) mx = fmaxf(mx, __shfl_xor(mx, m2));
      float sum = 0.0f;
#pragma unroll
      for (int nt = 0; nt < 4; ++nt) {
        float e = __expf(s[mt][nt][i] - mx);
        s[mt][nt][i] = e;
        sum += e;
      }
#pragma unroll
      for (int m2 = 1; m2 < 16; m2 <<= 1) sum += __shfl_xor(sum, m2);
      float inv = 1.0f / sum;
#pragma unroll
      for (int nt = 0; nt < 4; ++nt) s[mt][nt][i] *= inv;
    }
  // P -> LDS (bf16) to re-fragment for PV
#pragma unroll
  for (int mt = 0; mt < 4; ++mt)
#pragma unroll
    for (int nt = 0; nt < 4; ++nt)
#pragma unroll
      for (int i = 0; i < 4; ++i) {
        int r = mt * 16 + g * 4 + i, j = nt * 16 + c;
        Pl[w][r * 72 + j] = f2bf(s[mt][nt][i]);
      }
  __syncthreads();
  // PV: O[64x32] = P[64x64] @ V[64x32]
  f32x4 o[4][2] = {};
#pragma unroll
  for (int kk = 0; kk < 2; ++kk) {
    bf16x8 vb[2];
#pragma unroll
    for (int n2 = 0; n2 < 2; ++n2)
      vb[n2] = *(const bf16x8*)&Vt[w][(n2 * 16 + c) * 72 + kk * 32 + g * 8];
#pragma unroll
    for (int mt = 0; mt < 4; ++mt) {
      bf16x8 pa = *(const bf16x8*)&Pl[w][(mt * 16 + c) * 72 + kk * 32 + g * 8];
#pragma unroll
      for (int n2 = 0; n2 < 2; ++n2)
        o[mt][n2] = __builtin_amdgcn_mfma_f32_16x16x32_bf16(pa, vb[n2], o[mt][n2], 0, 0, 0);
    }
  }
#pragma unroll
  for (int mt = 0; mt < 4; ++mt)
#pragma unroll
    for (int n2 = 0; n2 < 2; ++n2)
#pragma unroll
      for (int i = 0; i < 4; ++i) {
        int r = mt * 16 + g * 4 + i;
        if (r < 49) {
          int d = n2 * 16 + c;
          ao[((size_t)win * 49 + r) * 1024 + h * 32 + d] = f2bf(o[mt][n2][i]);
        }
      }
}

// ---------------- launch ----------------
extern "C" void kernel_launch(void* const* d_in, const int* in_sizes, int n_in,
                              void* d_out, int out_size, void* d_ws, size_t ws_size,
                              hipStream_t stream) {
  (void)in_sizes; (void)n_in; (void)out_size; (void)ws_size;
  const float* x = (const float*)d_in[0];
  const float* v = (const float*)d_in[1];
  const float* n1g = (const float*)d_in[3];
  const float* n1b = (const float*)d_in[4];
  const float* qkw = (const float*)d_in[5];
  const float* qkb = (const float*)d_in[6];
  const float* rpb = (const float*)d_in[7];
  const float* pjw = (const float*)d_in[8];
  const float* pjb = (const float*)d_in[9];
  const float* n2g = (const float*)d_in[10];
  const float* n2b = (const float*)d_in[11];
  const float* f1w = (const float*)d_in[12];
  const float* f1b = (const float*)d_in[13];
  const float* f2w = (const float*)d_in[14];
  const float* f2b = (const float*)d_in[15];
  char* ws = (char*)d_ws;
  // Peak workspace: ~169 MiB
  short* w_qk = (short*)(ws + 0);                    //  4.0 MB
  short* w_pj = (short*)(ws + 4194304);              //  2.0 MB
  short* w_f1 = (short*)(ws + 6291456);              //  8.0 MB
  short* w_f2 = (short*)(ws + 14680064);             //  8.0 MB
  short* xnw  = (short*)(ws + 23068672);             // 50 MB  [ln1 -> qk gemm]
  short* qkbuf= (short*)(ws + 74448896);             // 100 MB [qk gemm -> attn]
  short* aob  = (short*)(ws + 23068672);             // 50 MB  overlays xnw [attn -> proj]
  short* xn2  = (short*)(ws + 23068672);             // 50 MB  overlays aob [ln2 -> fc1]
  short* h1   = (short*)(ws + 74448896);             // 100 MB overlays qkbuf [fc1 -> fc2, per chunk]
  float* out = (float*)d_out;                        // also holds x2 (attn residual)

  cast_qkw_kernel<<<2048, 256, 0, stream>>>(qkw, w_qk);
  cast_kernel<<<1024, 256, 0, stream>>>(pjw, w_pj);
  cast_kernel<<<4096, 256, 0, stream>>>(f1w, w_f1);
  cast_kernel<<<4096, 256, 0, stream>>>(f2w, w_f2);
  ln1_permute_kernel<<<25088, 256, 0, stream>>>(x, n1g, n1b, xnw);
  gemm_bt<0><<<dim3(196, 16), 256, 0, stream>>>(xnw, w_qk, qkb, nullptr, qkbuf, 2048, 1024);
  attn_kernel<<<4096, 256, 0, stream>>>(qkbuf, v, rpb, aob);
  gemm_bt<1><<<dim3(196, 8), 256, 0, stream>>>(aob, w_pj, pjb, x, out, 1024, 1024);
  ln2_kernel<<<25088, 256, 0, stream>>>(out, n2g, n2b, xn2);
  // MLP in 2 M-chunks of 12544 rows (hidden buffer reuses dead qkbuf region)
  for (int ch = 0; ch < 2; ++ch) {
    const short* a1 = xn2 + (size_t)ch * 12544 * 1024;
    float* o2 = out + (size_t)ch * 12544 * 1024;
    gemm_bt<2><<<dim3(98, 32), 256, 0, stream>>>(a1, w_f1, f1b, nullptr, h1, 4096, 1024);
    gemm_bt<3><<<dim3(98, 8), 256, 0, stream>>>(h1, w_f2, f2b, o2, o2, 1024, 4096);
  }
}

// Round 5
// 1101.937 us; speedup vs baseline: 1.2020x; 1.1410x over previous
//
#include <hip/hip_runtime.h>
#include <math.h>

typedef __attribute__((ext_vector_type(8))) short bf16x8;
typedef __attribute__((ext_vector_type(4))) short short4v;
typedef __attribute__((ext_vector_type(4))) float f32x4;

#define SCALE 0.17677669529663687f  // 32^-0.5

__device__ __forceinline__ short f2bf(float f) {
  unsigned u = __builtin_bit_cast(unsigned, f);
  unsigned r = u + 0x7fffu + ((u >> 16) & 1u);
  return (short)(r >> 16);
}

// async global->LDS, 16B per lane (dest = wave-uniform base + lane*16)
__device__ __forceinline__ void gll16(const short* g, short* l) {
  __builtin_amdgcn_global_load_lds(
      (const __attribute__((address_space(1))) unsigned int*)g,
      (__attribute__((address_space(3))) unsigned int*)l, 16, 0, 0);
}

// ---------------- weight casts ----------------
__global__ __launch_bounds__(256) void cast_qkw_kernel(const float* __restrict__ src,
                                                       short* __restrict__ dst) {
  size_t i = (size_t)blockIdx.x * 256 + threadIdx.x;
  f32x4 v = *(const f32x4*)(src + i * 4);
  float sc = (i * 4 < (size_t)1024 * 1024) ? SCALE : 1.0f;  // q out-rows get scale
  short4v o;
#pragma unroll
  for (int j = 0; j < 4; ++j) o[j] = f2bf(v[j] * sc);
  *(short4v*)(dst + i * 4) = o;
}

__global__ __launch_bounds__(256) void cast_kernel(const float* __restrict__ src,
                                                   short* __restrict__ dst) {
  size_t i = (size_t)blockIdx.x * 256 + threadIdx.x;
  f32x4 v = *(const f32x4*)(src + i * 4);
  short4v o;
#pragma unroll
  for (int j = 0; j < 4; ++j) o[j] = f2bf(v[j]);
  *(short4v*)(dst + i * 4) = o;
}

// ---------------- LN1 + shift + window-partition ----------------
__global__ __launch_bounds__(256) void ln1_permute_kernel(
    const float* __restrict__ x,
    const float* __restrict__ g1, const float* __restrict__ b1,
    short* __restrict__ xnw) {
  int r = blockIdx.x;
  int b = r / 3136, rem = r % 3136;
  int wi = rem / 49, n = rem % 49;
  int hs = (wi >> 3) * 7 + n / 7, wsf = (wi & 7) * 7 + n % 7;
  int ho = hs + 3; if (ho >= 56) ho -= 56;
  int wo = wsf + 3; if (wo >= 56) wo -= 56;
  size_t src = ((size_t)b * 3136 + ho * 56 + wo) * 1024;
  int t = threadIdx.x;
  f32x4 xv = *(const f32x4*)(x + src + t * 4);
  float s = xv[0] + xv[1] + xv[2] + xv[3];
  float s2 = xv[0] * xv[0] + xv[1] * xv[1] + xv[2] * xv[2] + xv[3] * xv[3];
#pragma unroll
  for (int m = 1; m < 64; m <<= 1) { s += __shfl_xor(s, m); s2 += __shfl_xor(s2, m); }
  __shared__ float red[8];
  int w = t >> 6;
  if ((t & 63) == 0) { red[w * 2] = s; red[w * 2 + 1] = s2; }
  __syncthreads();
  float ts = red[0] + red[2] + red[4] + red[6];
  float ts2 = red[1] + red[3] + red[5] + red[7];
  float mu = ts * (1.0f / 1024.0f);
  float var = ts2 * (1.0f / 1024.0f) - mu * mu;
  float rs = rsqrtf(var + 1e-5f);
  short4v xo;
#pragma unroll
  for (int j = 0; j < 4; ++j) {
    int cc = t * 4 + j;
    xo[j] = f2bf((xv[j] - mu) * rs * g1[cc] + b1[cc]);
  }
  *(short4v*)(xnw + (size_t)r * 1024 + t * 4) = xo;
}

// ---------------- LN2 ----------------
__global__ __launch_bounds__(256) void ln2_kernel(const float* __restrict__ x2,
                                                  const float* __restrict__ g2,
                                                  const float* __restrict__ b2,
                                                  short* __restrict__ xn2) {
  int r = blockIdx.x;
  size_t src = (size_t)r * 1024;
  int t = threadIdx.x;
  f32x4 xv = *(const f32x4*)(x2 + src + t * 4);
  float s = xv[0] + xv[1] + xv[2] + xv[3];
  float s2 = xv[0] * xv[0] + xv[1] * xv[1] + xv[2] * xv[2] + xv[3] * xv[3];
#pragma unroll
  for (int m = 1; m < 64; m <<= 1) { s += __shfl_xor(s, m); s2 += __shfl_xor(s2, m); }
  __shared__ float red[8];
  int w = t >> 6;
  if ((t & 63) == 0) { red[w * 2] = s; red[w * 2 + 1] = s2; }
  __syncthreads();
  float ts = red[0] + red[2] + red[4] + red[6];
  float ts2 = red[1] + red[3] + red[5] + red[7];
  float mu = ts * (1.0f / 1024.0f);
  float var = ts2 * (1.0f / 1024.0f) - mu * mu;
  float rs = rsqrtf(var + 1e-5f);
  short4v xo;
#pragma unroll
  for (int j = 0; j < 4; ++j) {
    int cc = t * 4 + j;
    xo[j] = f2bf((xv[j] - mu) * rs * g2[cc] + b2[cc]);
  }
  *(short4v*)(xn2 + src + t * 4) = xo;
}

// ---------------- 256x256 8-phase bf16 MFMA GEMM (T1+T2+T3+T4+T5) ----------------
// C[M,N] = A[M,K] @ Bt[N,K]^T. 512 threads = 8 waves (2M x 4N), per-wave 128x64 out.
// K-tile 64 = 2 k-slices of 32. LDS 128KiB: 2 dbuf x {A[256][32]ks0, A ks1, B ks0, B ks1} (16KiB each).
// st_16x32 XOR swizzle applied via pre-swizzled GLOBAL source (gll writes linear) + swizzled ds_read.
// Odd phases stage one kslice-pair (4 gll16) + s_waitcnt vmcnt(8); never vmcnt(0) mid-loop.
// EPI: 0 = qk (bias, pre-scaled, bf16)  1 = proj (bias + shortcut, window->orig scatter, f32)
//      2 = fc1 (bias + exact gelu, bf16)  3 = fc2 (bias + residual, f32; add0 may alias out)
template <int EPI>
__global__ __launch_bounds__(512, 2) void gemm8(const short* __restrict__ A,
                                                const short* __restrict__ Bt,
                                                const float* __restrict__ bias,
                                                const float* __restrict__ add0,
                                                void* __restrict__ out, int N, int K) {
  __shared__ __align__(16) short lds[65536];  // 128 KiB
  char* basec = (char*)lds;
  int t = threadIdx.x;
  int l = t & 63;
  int w = t >> 6;
  int wm = w >> 2, wn = w & 3;
  int g = l >> 4, c = l & 15;
  // bijective XCD-chunked swizzle (works for nwg % 8 != 0)
  int nwg = gridDim.x * gridDim.y;
  int orig = blockIdx.y * gridDim.x + blockIdx.x;
  int q = nwg >> 3, rr = nwg & 7, xcd = orig & 7, idx = orig >> 3;
  int swz = (xcd < rr ? xcd * (q + 1) : rr * (q + 1) + (xcd - rr) * q) + idx;
  int bx = swz % gridDim.x, by = swz / gridDim.x;
  const short* Ab = A + (size_t)bx * 256 * K;
  const short* Bb = Bt + (size_t)by * 256 * K;
  // staging chunk precompute: region = [256 rows][32 cols] bf16 (64B rows, 16KiB).
  // chunk j covers LDS bytes o..o+16; global src pre-swizzled so swizzled ds_read sees logical layout.
  int o0 = t * 16, o1 = 8192 + t * 16;
  int ol0 = o0 ^ (((o0 >> 9) & 1) << 5);
  int ol1 = o1 ^ (((o1 >> 9) & 1) << 5);
  size_t off0 = (size_t)(ol0 >> 6) * K + ((ol0 & 63) >> 1);
  size_t off1 = (size_t)(ol1 >> 6) * K + ((ol1 & 63) >> 1);
  int NT = K >> 6;   // K-tiles of 64
  int NI = NT >> 1;  // iterations (2 K-tiles each)

  f32x4 acc[8][4] = {};
  bf16x8 af[8], bf2[2];

#define STAGE_KS(db, ks, tt)                                           \
  do {                                                                 \
    size_t kb = (size_t)(tt) * 64 + (ks) * 32;                         \
    short* rA = (short*)(basec + (db) * 65536 + (ks) * 16384);         \
    short* rB = (short*)(basec + (db) * 65536 + 32768 + (ks) * 16384); \
    gll16(Ab + kb + off0, rA + t * 8);                                 \
    gll16(Ab + kb + off1, rA + 4096 + t * 8);                          \
    gll16(Bb + kb + off0, rB + t * 8);                                 \
    gll16(Bb + kb + off1, rB + 4096 + t * 8);                          \
  } while (0)

#define DSR_A(db, ks)                                                   \
  do {                                                                  \
    _Pragma("unroll") for (int m = 0; m < 8; ++m) {                     \
      int rrow = wm * 128 + m * 16 + c;                                 \
      int lin = rrow * 64 + g * 16;                                     \
      int sw = lin ^ (((lin >> 9) & 1) << 5);                           \
      af[m] = *(const bf16x8*)(basec + (db) * 65536 + (ks) * 16384 + sw); \
    }                                                                   \
  } while (0)

#define DSR_B(db, ks, nh)                                               \
  do {                                                                  \
    _Pragma("unroll") for (int n2 = 0; n2 < 2; ++n2) {                  \
      int rB2 = wn * 64 + ((nh) * 2 + n2) * 16 + c;                     \
      int lin = rB2 * 64 + g * 16;                                      \
      int sw = lin ^ (((lin >> 9) & 1) << 5);                           \
      bf2[n2] = *(const bf16x8*)(basec + (db) * 65536 + 32768 + (ks) * 16384 + sw); \
    }                                                                   \
  } while (0)

#define SB __builtin_amdgcn_sched_barrier(0)

#define PHASE(db, ks, nh, DOSTAGE, sdb, sks, stt)                  \
  do {                                                             \
    if (DOSTAGE) {                                                 \
      STAGE_KS(sdb, sks, stt);                                     \
      asm volatile("s_waitcnt vmcnt(8)" ::: "memory");             \
    }                                                              \
    SB;                                                            \
    __builtin_amdgcn_s_barrier();                                  \
    SB;                                                            \
    if ((nh) == 0) DSR_A(db, ks);                                  \
    DSR_B(db, ks, nh);                                             \
    asm volatile("s_waitcnt lgkmcnt(0)" ::: "memory");             \
    SB;                                                            \
    __builtin_amdgcn_s_setprio(1);                                 \
    _Pragma("unroll") for (int m = 0; m < 8; ++m)                  \
      _Pragma("unroll") for (int n2 = 0; n2 < 2; ++n2)             \
        acc[m][(nh) * 2 + n2] = __builtin_amdgcn_mfma_f32_16x16x32_bf16( \
            af[m], bf2[n2], acc[m][(nh) * 2 + n2], 0, 0, 0);       \
    __builtin_amdgcn_s_setprio(0);                                 \
    SB;                                                            \
    __builtin_amdgcn_s_barrier();                                  \
    SB;                                                            \
  } while (0)

  // prologue: T0 both kslices -> dbuf0, T1.ks0 -> dbuf1 (12 loads in flight)
  STAGE_KS(0, 0, 0);
  STAGE_KS(0, 1, 0);
  STAGE_KS(1, 0, 1);

  for (int it = 0; it < NI; ++it) {
    int t1 = 2 * it + 1;
    int nt2 = 2 * it + 2; if (nt2 > NT - 1) nt2 = NT - 1;
    int nt3 = 2 * it + 3; if (nt3 > NT - 1) nt3 = NT - 1;
    PHASE(0, 0, 0, 1, 1, 1, t1);   // P1: stage T1.ks1 -> dbuf1.ks1 (read at P7)
    PHASE(0, 0, 1, 0, 0, 0, 0);    // P2
    PHASE(0, 1, 0, 1, 0, 0, nt2);  // P3: stage T2.ks0 -> dbuf0.ks0 (freed after P2)
    PHASE(0, 1, 1, 0, 0, 0, 0);    // P4
    PHASE(1, 0, 0, 1, 0, 1, nt2);  // P5: stage T2.ks1 -> dbuf0.ks1 (freed after P4)
    PHASE(1, 0, 1, 0, 0, 0, 0);    // P6
    PHASE(1, 1, 0, 1, 1, 0, nt3);  // P7: stage T3.ks0 -> dbuf1.ks0 (freed after P6)
    PHASE(1, 1, 1, 0, 0, 0, 0);    // P8
  }
  asm volatile("s_waitcnt vmcnt(0)" ::: "memory");
#undef PHASE
#undef SB
#undef DSR_B
#undef DSR_A
#undef STAGE_KS

  int mb = bx * 256 + wm * 128;
  int nb = by * 256 + wn * 64;
#pragma unroll
  for (int m = 0; m < 8; ++m) {
#pragma unroll
    for (int i = 0; i < 4; ++i) {
      int row = mb + m * 16 + g * 4 + i;
      size_t orow = row;
      if (EPI == 1) {  // window order -> original order
        int bb = row / 3136, rem = row % 3136;
        int wi = rem / 49, n = rem % 49;
        int hs = (wi >> 3) * 7 + n / 7, wf = (wi & 7) * 7 + n % 7;
        int ho = hs + 3; if (ho >= 56) ho -= 56;
        int wo = wf + 3; if (wo >= 56) wo -= 56;
        orow = (size_t)bb * 3136 + ho * 56 + wo;
      }
#pragma unroll
      for (int nf = 0; nf < 4; ++nf) {
        int col = nb + nf * 16 + c;
        float val = acc[m][nf][i];
        if (EPI == 0) {
          float bv = bias[col] * (col < 1024 ? SCALE : 1.0f);
          ((short*)out)[(size_t)row * N + col] = f2bf(val + bv);
        } else if (EPI == 1) {
          ((float*)out)[orow * 1024 + col] = val + bias[col] + add0[orow * 1024 + col];
        } else if (EPI == 2) {
          float hv = val + bias[col];
          ((short*)out)[(size_t)row * N + col] = f2bf(0.5f * hv * (1.0f + erff(hv * 0.70710678118f)));
        } else {
          float res = add0[(size_t)row * 1024 + col];
          ((float*)out)[(size_t)row * 1024 + col] = val + bias[col] + res;
        }
      }
    }
  }
}

// ---------------- windowed attention: 1 wave = 1 (window, head); V direct from f32 input ----------------
__global__ __launch_bounds__(256) void attn_kernel(const short* __restrict__ qk,
                                                   const float* __restrict__ v,
                                                   const float* __restrict__ rpb,
                                                   short* __restrict__ ao) {
  __shared__ __align__(16) float rpbt[32 * 169];  // [head][idx]
  __shared__ int cnt[49];
  __shared__ __align__(16) short Vt[4][32 * 72];  // [wave][d][j] transposed V, padded
  __shared__ __align__(16) short Pl[4][64 * 72];  // [wave][row][col] P, padded
  int t = threadIdx.x, l = t & 63, w = t >> 6;
  int win = blockIdx.x >> 3;
  int h = (blockIdx.x & 7) * 4 + w;
  for (int e = t; e < 169 * 32; e += 256) {
    int hh = e / 169, idx = e - hh * 169;
    rpbt[e] = rpb[idx * 32 + hh];
  }
  if (t < 49) {
    int wi = win & 63;
    int hs = (wi >> 3) * 7 + t / 7, wsf = (wi & 7) * 7 + t % 7;
    int rh = hs < 49 ? 0 : (hs < 53 ? 1 : 2);
    int rw = wsf < 49 ? 0 : (wsf < 53 ? 1 : 2);
    cnt[t] = rh * 3 + rw;
  }
  if (l < 49) {
    int wi = win & 63, b = win >> 6;
    int hs = (wi >> 3) * 7 + l / 7, wsf = (wi & 7) * 7 + l % 7;
    int ho = hs + 3; if (ho >= 56) ho -= 56;
    int wo = wsf + 3; if (wo >= 56) wo -= 56;
    const float* vp = v + ((size_t)b * 3136 + ho * 56 + wo) * 1024 + h * 32;
#pragma unroll
    for (int d4 = 0; d4 < 8; ++d4) {
      f32x4 vv = *(const f32x4*)(vp + d4 * 4);
#pragma unroll
      for (int j = 0; j < 4; ++j) Vt[w][(d4 * 4 + j) * 72 + l] = f2bf(vv[j]);
    }
  } else {
#pragma unroll
    for (int d = 0; d < 32; ++d) Vt[w][d * 72 + l] = 0;
  }
  __syncthreads();
  int g = l >> 4, c = l & 15;
  bf16x8 qf[4], kf[4];
#pragma unroll
  for (int mt = 0; mt < 4; ++mt) {
    int r = mt * 16 + c; if (r > 48) r = 48;
    qf[mt] = *(const bf16x8*)&qk[((size_t)win * 49 + r) * 2048 + h * 32 + g * 8];
  }
#pragma unroll
  for (int nt = 0; nt < 4; ++nt) {
    int j = nt * 16 + c; if (j > 48) j = 48;
    kf[nt] = *(const bf16x8*)&qk[((size_t)win * 49 + j) * 2048 + 1024 + h * 32 + g * 8];
  }
  f32x4 s[4][4] = {};
#pragma unroll
  for (int mt = 0; mt < 4; ++mt)
#pragma unroll
    for (int nt = 0; nt < 4; ++nt)
      s[mt][nt] = __builtin_amdgcn_mfma_f32_16x16x32_bf16(qf[mt], kf[nt], s[mt][nt], 0, 0, 0);
#pragma unroll
  for (int mt = 0; mt < 4; ++mt)
#pragma unroll
    for (int nt = 0; nt < 4; ++nt)
#pragma unroll
      for (int i = 0; i < 4; ++i) {
        int r = mt * 16 + g * 4 + i;
        int j = nt * 16 + c;
        float val = s[mt][nt][i];
        if (r < 49 && j < 49) {
          int idx = (r / 7 - j / 7 + 6) * 13 + (r % 7 - j % 7 + 6);
          val += rpbt[h * 169 + idx];
          if (cnt[r] != cnt[j]) val -= 100.0f;
        } else {
          val = -1e30f;
        }
        s[mt][nt][i] = val;
      }
#pragma unroll
  for (int mt = 0; mt < 4; ++mt)
#pragma unroll
    for (int i = 0; i < 4; ++i) {
      float mx = s[mt][0][i];
#pragma unroll
      for (int nt = 1; nt < 4; ++nt) mx = fmaxf(mx, s[mt][nt][i]);
#pragma unroll
      for (int m2 = 1; m2 < 16; m2 <<= 1) mx = fmaxf(mx, __shfl_xor(mx, m2));
      float sum = 0.0f;
#pragma unroll
      for (int nt = 0; nt < 4; ++nt) {
        float e = __expf(s[mt][nt][i] - mx);
        s[mt][nt][i] = e;
        sum += e;
      }
#pragma unroll
      for (int m2 = 1; m2 < 16; m2 <<= 1) sum += __shfl_xor(sum, m2);
      float inv = 1.0f / sum;
#pragma unroll
      for (int nt = 0; nt < 4; ++nt) s[mt][nt][i] *= inv;
    }
#pragma unroll
  for (int mt = 0; mt < 4; ++mt)
#pragma unroll
    for (int nt = 0; nt < 4; ++nt)
#pragma unroll
      for (int i = 0; i < 4; ++i) {
        int r = mt * 16 + g * 4 + i, j = nt * 16 + c;
        Pl[w][r * 72 + j] = f2bf(s[mt][nt][i]);
      }
  __syncthreads();
  f32x4 o[4][2] = {};
#pragma unroll
  for (int kk = 0; kk < 2; ++kk) {
    bf16x8 vb[2];
#pragma unroll
    for (int n2 = 0; n2 < 2; ++n2)
      vb[n2] = *(const bf16x8*)&Vt[w][(n2 * 16 + c) * 72 + kk * 32 + g * 8];
#pragma unroll
    for (int mt = 0; mt < 4; ++mt) {
      bf16x8 pa = *(const bf16x8*)&Pl[w][(mt * 16 + c) * 72 + kk * 32 + g * 8];
#pragma unroll
      for (int n2 = 0; n2 < 2; ++n2)
        o[mt][n2] = __builtin_amdgcn_mfma_f32_16x16x32_bf16(pa, vb[n2], o[mt][n2], 0, 0, 0);
    }
  }
#pragma unroll
  for (int mt = 0; mt < 4; ++mt)
#pragma unroll
    for (int n2 = 0; n2 < 2; ++n2)
#pragma unroll
      for (int i = 0; i < 4; ++i) {
        int r = mt * 16 + g * 4 + i;
        if (r < 49) {
          int d = n2 * 16 + c;
          ao[((size_t)win * 49 + r) * 1024 + h * 32 + d] = f2bf(o[mt][n2][i]);
        }
      }
}

// ---------------- launch ----------------
extern "C" void kernel_launch(void* const* d_in, const int* in_sizes, int n_in,
                              void* d_out, int out_size, void* d_ws, size_t ws_size,
                              hipStream_t stream) {
  (void)in_sizes; (void)n_in; (void)out_size; (void)ws_size;
  const float* x = (const float*)d_in[0];
  const float* v = (const float*)d_in[1];
  const float* n1g = (const float*)d_in[3];
  const float* n1b = (const float*)d_in[4];
  const float* qkw = (const float*)d_in[5];
  const float* qkb = (const float*)d_in[6];
  const float* rpb = (const float*)d_in[7];
  const float* pjw = (const float*)d_in[8];
  const float* pjb = (const float*)d_in[9];
  const float* n2g = (const float*)d_in[10];
  const float* n2b = (const float*)d_in[11];
  const float* f1w = (const float*)d_in[12];
  const float* f1b = (const float*)d_in[13];
  const float* f2w = (const float*)d_in[14];
  const float* f2b = (const float*)d_in[15];
  char* ws = (char*)d_ws;
  // Peak workspace: ~169 MiB
  short* w_qk = (short*)(ws + 0);                    //  4.0 MB
  short* w_pj = (short*)(ws + 4194304);              //  2.0 MB
  short* w_f1 = (short*)(ws + 6291456);              //  8.0 MB
  short* w_f2 = (short*)(ws + 14680064);             //  8.0 MB
  short* xnw  = (short*)(ws + 23068672);             // 50 MB  [ln1 -> qk gemm]
  short* qkbuf= (short*)(ws + 74448896);             // 100 MB [qk gemm -> attn]
  short* aob  = (short*)(ws + 23068672);             // 50 MB  overlays xnw [attn -> proj]
  short* xn2  = (short*)(ws + 23068672);             // 50 MB  overlays aob [ln2 -> fc1]
  short* h1   = (short*)(ws + 74448896);             // 100 MB overlays qkbuf [fc1 -> fc2, per chunk]
  float* out = (float*)d_out;                        // also holds x2 (attn residual)

  cast_qkw_kernel<<<2048, 256, 0, stream>>>(qkw, w_qk);
  cast_kernel<<<1024, 256, 0, stream>>>(pjw, w_pj);
  cast_kernel<<<4096, 256, 0, stream>>>(f1w, w_f1);
  cast_kernel<<<4096, 256, 0, stream>>>(f2w, w_f2);
  ln1_permute_kernel<<<25088, 256, 0, stream>>>(x, n1g, n1b, xnw);
  gemm8<0><<<dim3(98, 8), 512, 0, stream>>>(xnw, w_qk, qkb, nullptr, qkbuf, 2048, 1024);
  attn_kernel<<<4096, 256, 0, stream>>>(qkbuf, v, rpb, aob);
  gemm8<1><<<dim3(98, 4), 512, 0, stream>>>(aob, w_pj, pjb, x, out, 1024, 1024);
  ln2_kernel<<<25088, 256, 0, stream>>>(out, n2g, n2b, xn2);
  // MLP in 2 M-chunks of 12544 rows (hidden buffer reuses dead qkbuf region)
  for (int ch = 0; ch < 2; ++ch) {
    const short* a1 = xn2 + (size_t)ch * 12544 * 1024;
    float* o2 = out + (size_t)ch * 12544 * 1024;
    gemm8<2><<<dim3(49, 16), 512, 0, stream>>>(a1, w_f1, f1b, nullptr, h1, 4096, 1024);
    gemm8<3><<<dim3(49, 4), 512, 0, stream>>>(h1, w_f2, f2b, o2, o2, 1024, 4096);
  }
}

// Round 6
// 1069.539 us; speedup vs baseline: 1.2384x; 1.0303x over previous
//
#include <hip/hip_runtime.h>
#include <math.h>

typedef __attribute__((ext_vector_type(8))) short bf16x8;
typedef __attribute__((ext_vector_type(4))) short short4v;
typedef __attribute__((ext_vector_type(4))) float f32x4;

#define SCALE 0.17677669529663687f  // 32^-0.5

__device__ __forceinline__ short f2bf(float f) {
  unsigned u = __builtin_bit_cast(unsigned, f);
  unsigned r = u + 0x7fffu + ((u >> 16) & 1u);
  return (short)(r >> 16);
}

// async global->LDS, 16B per lane (dest = wave-uniform base + lane*16)
__device__ __forceinline__ void gll16(const short* g, short* l) {
  __builtin_amdgcn_global_load_lds(
      (const __attribute__((address_space(1))) unsigned int*)g,
      (__attribute__((address_space(3))) unsigned int*)l, 16, 0, 0);
}

// ---------------- weight casts ----------------
__global__ __launch_bounds__(256) void cast_qkw_kernel(const float* __restrict__ src,
                                                       short* __restrict__ dst) {
  size_t i = (size_t)blockIdx.x * 256 + threadIdx.x;
  f32x4 v = *(const f32x4*)(src + i * 4);
  float sc = (i * 4 < (size_t)1024 * 1024) ? SCALE : 1.0f;  // q out-rows get scale
  short4v o;
#pragma unroll
  for (int j = 0; j < 4; ++j) o[j] = f2bf(v[j] * sc);
  *(short4v*)(dst + i * 4) = o;
}

__global__ __launch_bounds__(256) void cast_kernel(const float* __restrict__ src,
                                                   short* __restrict__ dst) {
  size_t i = (size_t)blockIdx.x * 256 + threadIdx.x;
  f32x4 v = *(const f32x4*)(src + i * 4);
  short4v o;
#pragma unroll
  for (int j = 0; j < 4; ++j) o[j] = f2bf(v[j]);
  *(short4v*)(dst + i * 4) = o;
}

// ---------------- LN1 + shift + window-partition ----------------
__global__ __launch_bounds__(256) void ln1_permute_kernel(
    const float* __restrict__ x,
    const float* __restrict__ g1, const float* __restrict__ b1,
    short* __restrict__ xnw) {
  int r = blockIdx.x;
  int b = r / 3136, rem = r % 3136;
  int wi = rem / 49, n = rem % 49;
  int hs = (wi >> 3) * 7 + n / 7, wsf = (wi & 7) * 7 + n % 7;
  int ho = hs + 3; if (ho >= 56) ho -= 56;
  int wo = wsf + 3; if (wo >= 56) wo -= 56;
  size_t src = ((size_t)b * 3136 + ho * 56 + wo) * 1024;
  int t = threadIdx.x;
  f32x4 xv = *(const f32x4*)(x + src + t * 4);
  float s = xv[0] + xv[1] + xv[2] + xv[3];
  float s2 = xv[0] * xv[0] + xv[1] * xv[1] + xv[2] * xv[2] + xv[3] * xv[3];
#pragma unroll
  for (int m = 1; m < 64; m <<= 1) { s += __shfl_xor(s, m); s2 += __shfl_xor(s2, m); }
  __shared__ float red[8];
  int w = t >> 6;
  if ((t & 63) == 0) { red[w * 2] = s; red[w * 2 + 1] = s2; }
  __syncthreads();
  float ts = red[0] + red[2] + red[4] + red[6];
  float ts2 = red[1] + red[3] + red[5] + red[7];
  float mu = ts * (1.0f / 1024.0f);
  float var = ts2 * (1.0f / 1024.0f) - mu * mu;
  float rs = rsqrtf(var + 1e-5f);
  short4v xo;
#pragma unroll
  for (int j = 0; j < 4; ++j) {
    int cc = t * 4 + j;
    xo[j] = f2bf((xv[j] - mu) * rs * g1[cc] + b1[cc]);
  }
  *(short4v*)(xnw + (size_t)r * 1024 + t * 4) = xo;
}

// ---------------- LN2 ----------------
__global__ __launch_bounds__(256) void ln2_kernel(const float* __restrict__ x2,
                                                  const float* __restrict__ g2,
                                                  const float* __restrict__ b2,
                                                  short* __restrict__ xn2) {
  int r = blockIdx.x;
  size_t src = (size_t)r * 1024;
  int t = threadIdx.x;
  f32x4 xv = *(const f32x4*)(x2 + src + t * 4);
  float s = xv[0] + xv[1] + xv[2] + xv[3];
  float s2 = xv[0] * xv[0] + xv[1] * xv[1] + xv[2] * xv[2] + xv[3] * xv[3];
#pragma unroll
  for (int m = 1; m < 64; m <<= 1) { s += __shfl_xor(s, m); s2 += __shfl_xor(s2, m); }
  __shared__ float red[8];
  int w = t >> 6;
  if ((t & 63) == 0) { red[w * 2] = s; red[w * 2 + 1] = s2; }
  __syncthreads();
  float ts = red[0] + red[2] + red[4] + red[6];
  float ts2 = red[1] + red[3] + red[5] + red[7];
  float mu = ts * (1.0f / 1024.0f);
  float var = ts2 * (1.0f / 1024.0f) - mu * mu;
  float rs = rsqrtf(var + 1e-5f);
  short4v xo;
#pragma unroll
  for (int j = 0; j < 4; ++j) {
    int cc = t * 4 + j;
    xo[j] = f2bf((xv[j] - mu) * rs * g2[cc] + b2[cc]);
  }
  *(short4v*)(xn2 + src + t * 4) = xo;
}

// ---------------- 256x256 8-phase bf16 MFMA GEMM (T1+T2+T3+T4+T5) ----------------
// C[M,N] = A[M,K] @ Bt[N,K]^T. 512 threads = 8 waves (2M x 4N), per-wave 128x64 out.
// K-tile 64 = 2 k-slices of 32. LDS 128KiB: 2 dbuf x {A ks0, A ks1, B ks0, B ks1} (16KiB each).
// st_16x32 XOR swizzle via pre-swizzled GLOBAL source (gll writes linear) + swizzled ds_read.
// ds_reads issued BEFORE barrier1 (m201 interleave); data-readiness guaranteed by vmcnt(8)
// at each staging phase: <=2 batches outstanding => batch read 2 phases later is confirmed
// at least one barrier before its read issue (audited P1..P8, prologue, tail).
// EPI: 0 = qk (bias, pre-scaled, bf16)  1 = proj (bias + shortcut, window->orig scatter, f32)
//      2 = fc1 (bias + exact gelu, bf16)  3 = fc2 (bias + residual, f32; add0 may alias out)
template <int EPI>
__global__ __launch_bounds__(512, 2) void gemm8(const short* __restrict__ A,
                                                const short* __restrict__ Bt,
                                                const float* __restrict__ bias,
                                                const float* __restrict__ add0,
                                                void* __restrict__ out, int N, int K) {
  __shared__ __align__(16) short lds[65536];  // 128 KiB
  char* basec = (char*)lds;
  int t = threadIdx.x;
  int l = t & 63;
  int w = t >> 6;
  int wm = w >> 2, wn = w & 3;
  int g = l >> 4, c = l & 15;
  // bijective XCD-chunked swizzle (works for nwg % 8 != 0)
  int nwg = gridDim.x * gridDim.y;
  int orig = blockIdx.y * gridDim.x + blockIdx.x;
  int q = nwg >> 3, rr = nwg & 7, xcd = orig & 7, idx = orig >> 3;
  int swz = (xcd < rr ? xcd * (q + 1) : rr * (q + 1) + (xcd - rr) * q) + idx;
  int bx = swz % gridDim.x, by = swz / gridDim.x;
  const short* Ab = A + (size_t)bx * 256 * K;
  const short* Bb = Bt + (size_t)by * 256 * K;
  // staging: region = [256 rows][32 cols] bf16 (64B rows, 16KiB); source pre-swizzled (st_16x32 inv)
  int o0 = t * 16, o1 = 8192 + t * 16;
  int ol0 = o0 ^ (((o0 >> 9) & 1) << 5);
  int ol1 = o1 ^ (((o1 >> 9) & 1) << 5);
  size_t off0 = (size_t)(ol0 >> 6) * K + ((ol0 & 63) >> 1);
  size_t off1 = (size_t)(ol1 >> 6) * K + ((ol1 & 63) >> 1);
  int NT = K >> 6;   // K-tiles of 64
  int NI = NT >> 1;  // iterations (2 K-tiles each)

  f32x4 acc[8][4] = {};
  bf16x8 af[8], bf2[2];

#define STAGE_KS(db, ks, tt)                                           \
  do {                                                                 \
    size_t kb = (size_t)(tt) * 64 + (ks) * 32;                         \
    short* rA = (short*)(basec + (db) * 65536 + (ks) * 16384);         \
    short* rB = (short*)(basec + (db) * 65536 + 32768 + (ks) * 16384); \
    gll16(Ab + kb + off0, rA + t * 8);                                 \
    gll16(Ab + kb + off1, rA + 4096 + t * 8);                          \
    gll16(Bb + kb + off0, rB + t * 8);                                 \
    gll16(Bb + kb + off1, rB + 4096 + t * 8);                          \
  } while (0)

#define DSR_A(db, ks)                                                   \
  do {                                                                  \
    _Pragma("unroll") for (int m = 0; m < 8; ++m) {                     \
      int rrow = wm * 128 + m * 16 + c;                                 \
      int lin = rrow * 64 + g * 16;                                     \
      int sw = lin ^ (((lin >> 9) & 1) << 5);                           \
      af[m] = *(const bf16x8*)(basec + (db) * 65536 + (ks) * 16384 + sw); \
    }                                                                   \
  } while (0)

#define DSR_B(db, ks, nh)                                               \
  do {                                                                  \
    _Pragma("unroll") for (int n2 = 0; n2 < 2; ++n2) {                  \
      int rB2 = wn * 64 + ((nh) * 2 + n2) * 16 + c;                     \
      int lin = rB2 * 64 + g * 16;                                      \
      int sw = lin ^ (((lin >> 9) & 1) << 5);                           \
      bf2[n2] = *(const bf16x8*)(basec + (db) * 65536 + 32768 + (ks) * 16384 + sw); \
    }                                                                   \
  } while (0)

#define SB __builtin_amdgcn_sched_barrier(0)

// Per phase: {ds_read fragments ; stage+vmcnt(8)} -> barrier -> lgkmcnt(0) -> MFMA -> barrier.
// Reads target data confirmed landed by the vmcnt(8)+barrier of >=2 phases earlier.
#define PHASE(db, ks, nh, DOSTAGE, sdb, sks, stt)                  \
  do {                                                             \
    if ((nh) == 0) DSR_A(db, ks);                                  \
    DSR_B(db, ks, nh);                                             \
    if (DOSTAGE) {                                                 \
      STAGE_KS(sdb, sks, stt);                                     \
      asm volatile("s_waitcnt vmcnt(8)" ::: "memory");             \
    }                                                              \
    SB;                                                            \
    __builtin_amdgcn_s_barrier();                                  \
    SB;                                                            \
    asm volatile("s_waitcnt lgkmcnt(0)" ::: "memory");             \
    SB;                                                            \
    __builtin_amdgcn_s_setprio(1);                                 \
    _Pragma("unroll") for (int m = 0; m < 8; ++m)                  \
      _Pragma("unroll") for (int n2 = 0; n2 < 2; ++n2)             \
        acc[m][(nh) * 2 + n2] = __builtin_amdgcn_mfma_f32_16x16x32_bf16( \
            af[m], bf2[n2], acc[m][(nh) * 2 + n2], 0, 0, 0);       \
    __builtin_amdgcn_s_setprio(0);                                 \
    SB;                                                            \
    __builtin_amdgcn_s_barrier();                                  \
    SB;                                                            \
  } while (0)

  // prologue: T0 both kslices -> dbuf0, T1.ks0 -> dbuf1; confirm batch0 (d0k0) landed
  STAGE_KS(0, 0, 0);
  STAGE_KS(0, 1, 0);
  STAGE_KS(1, 0, 1);
  asm volatile("s_waitcnt vmcnt(8)" ::: "memory");
  SB;
  __builtin_amdgcn_s_barrier();
  SB;

  for (int it = 0; it < NI; ++it) {
    int t1 = 2 * it + 1;
    int nt2 = 2 * it + 2; if (nt2 > NT - 1) nt2 = NT - 1;
    int nt3 = 2 * it + 3; if (nt3 > NT - 1) nt3 = NT - 1;
    PHASE(0, 0, 0, 1, 1, 1, t1);   // P1: stage T1.ks1 -> d1k1 (read P7)
    PHASE(0, 0, 1, 0, 0, 0, 0);    // P2
    PHASE(0, 1, 0, 1, 0, 0, nt2);  // P3: stage T2.ks0 -> d0k0 (freed after P2)
    PHASE(0, 1, 1, 0, 0, 0, 0);    // P4
    PHASE(1, 0, 0, 1, 0, 1, nt2);  // P5: stage T2.ks1 -> d0k1 (freed after P4)
    PHASE(1, 0, 1, 0, 0, 0, 0);    // P6
    PHASE(1, 1, 0, 1, 1, 0, nt3);  // P7: stage T3.ks0 -> d1k0 (freed after P6)
    PHASE(1, 1, 1, 0, 0, 0, 0);    // P8
  }
  asm volatile("s_waitcnt vmcnt(0)" ::: "memory");
#undef PHASE
#undef SB
#undef DSR_B
#undef DSR_A
#undef STAGE_KS

  int mb = bx * 256 + wm * 128;
  int nb = by * 256 + wn * 64;
#pragma unroll
  for (int m = 0; m < 8; ++m) {
#pragma unroll
    for (int i = 0; i < 4; ++i) {
      int row = mb + m * 16 + g * 4 + i;
      size_t orow = row;
      if (EPI == 1) {  // window order -> original order
        int bb = row / 3136, rem = row % 3136;
        int wi = rem / 49, n = rem % 49;
        int hs = (wi >> 3) * 7 + n / 7, wf = (wi & 7) * 7 + n % 7;
        int ho = hs + 3; if (ho >= 56) ho -= 56;
        int wo = wf + 3; if (wo >= 56) wo -= 56;
        orow = (size_t)bb * 3136 + ho * 56 + wo;
      }
#pragma unroll
      for (int nf = 0; nf < 4; ++nf) {
        int col = nb + nf * 16 + c;
        float val = acc[m][nf][i];
        if (EPI == 0) {
          float bv = bias[col] * (col < 1024 ? SCALE : 1.0f);
          ((short*)out)[(size_t)row * N + col] = f2bf(val + bv);
        } else if (EPI == 1) {
          ((float*)out)[orow * 1024 + col] = val + bias[col] + add0[orow * 1024 + col];
        } else if (EPI == 2) {
          float hv = val + bias[col];
          ((short*)out)[(size_t)row * N + col] = f2bf(0.5f * hv * (1.0f + erff(hv * 0.70710678118f)));
        } else {
          float res = add0[(size_t)row * 1024 + col];
          ((float*)out)[(size_t)row * 1024 + col] = val + bias[col] + res;
        }
      }
    }
  }
}

// ---------------- windowed attention: 1 wave = 1 (window, head); V direct from f32 input ----------------
__global__ __launch_bounds__(256) void attn_kernel(const short* __restrict__ qk,
                                                   const float* __restrict__ v,
                                                   const float* __restrict__ rpb,
                                                   short* __restrict__ ao) {
  __shared__ __align__(16) float rpbt[32 * 169];  // [head][idx]
  __shared__ int cnt[49];
  __shared__ __align__(16) short Vt[4][32 * 72];  // [wave][d][j] transposed V, padded
  __shared__ __align__(16) short Pl[4][64 * 72];  // [wave][row][col] P, padded
  int t = threadIdx.x, l = t & 63, w = t >> 6;
  int win = blockIdx.x >> 3;
  int h = (blockIdx.x & 7) * 4 + w;
  for (int e = t; e < 169 * 32; e += 256) {
    int hh = e / 169, idx = e - hh * 169;
    rpbt[e] = rpb[idx * 32 + hh];
  }
  if (t < 49) {
    int wi = win & 63;
    int hs = (wi >> 3) * 7 + t / 7, wsf = (wi & 7) * 7 + t % 7;
    int rh = hs < 49 ? 0 : (hs < 53 ? 1 : 2);
    int rw = wsf < 49 ? 0 : (wsf < 53 ? 1 : 2);
    cnt[t] = rh * 3 + rw;
  }
  if (l < 49) {
    int wi = win & 63, b = win >> 6;
    int hs = (wi >> 3) * 7 + l / 7, wsf = (wi & 7) * 7 + l % 7;
    int ho = hs + 3; if (ho >= 56) ho -= 56;
    int wo = wsf + 3; if (wo >= 56) wo -= 56;
    const float* vp = v + ((size_t)b * 3136 + ho * 56 + wo) * 1024 + h * 32;
#pragma unroll
    for (int d4 = 0; d4 < 8; ++d4) {
      f32x4 vv = *(const f32x4*)(vp + d4 * 4);
#pragma unroll
      for (int j = 0; j < 4; ++j) Vt[w][(d4 * 4 + j) * 72 + l] = f2bf(vv[j]);
    }
  } else {
#pragma unroll
    for (int d = 0; d < 32; ++d) Vt[w][d * 72 + l] = 0;
  }
  __syncthreads();
  int g = l >> 4, c = l & 15;
  bf16x8 qf[4], kf[4];
#pragma unroll
  for (int mt = 0; mt < 4; ++mt) {
    int r = mt * 16 + c; if (r > 48) r = 48;
    qf[mt] = *(const bf16x8*)&qk[((size_t)win * 49 + r) * 2048 + h * 32 + g * 8];
  }
#pragma unroll
  for (int nt = 0; nt < 4; ++nt) {
    int j = nt * 16 + c; if (j > 48) j = 48;
    kf[nt] = *(const bf16x8*)&qk[((size_t)win * 49 + j) * 2048 + 1024 + h * 32 + g * 8];
  }
  f32x4 s[4][4] = {};
#pragma unroll
  for (int mt = 0; mt < 4; ++mt)
#pragma unroll
    for (int nt = 0; nt < 4; ++nt)
      s[mt][nt] = __builtin_amdgcn_mfma_f32_16x16x32_bf16(qf[mt], kf[nt], s[mt][nt], 0, 0, 0);
#pragma unroll
  for (int mt = 0; mt < 4; ++mt)
#pragma unroll
    for (int nt = 0; nt < 4; ++nt)
#pragma unroll
      for (int i = 0; i < 4; ++i) {
        int r = mt * 16 + g * 4 + i;
        int j = nt * 16 + c;
        float val = s[mt][nt][i];
        if (r < 49 && j < 49) {
          int idx = (r / 7 - j / 7 + 6) * 13 + (r % 7 - j % 7 + 6);
          val += rpbt[h * 169 + idx];
          if (cnt[r] != cnt[j]) val -= 100.0f;
        } else {
          val = -1e30f;
        }
        s[mt][nt][i] = val;
      }
#pragma unroll
  for (int mt = 0; mt < 4; ++mt)
#pragma unroll
    for (int i = 0; i < 4; ++i) {
      float mx = s[mt][0][i];
#pragma unroll
      for (int nt = 1; nt < 4; ++nt) mx = fmaxf(mx, s[mt][nt][i]);
#pragma unroll
      for (int m2 = 1; m2 < 16; m2 <<= 1) mx = fmaxf(mx, __shfl_xor(mx, m2));
      float sum = 0.0f;
#pragma unroll
      for (int nt = 0; nt < 4; ++nt) {
        float e = __expf(s[mt][nt][i] - mx);
        s[mt][nt][i] = e;
        sum += e;
      }
#pragma unroll
      for (int m2 = 1; m2 < 16; m2 <<= 1) sum += __shfl_xor(sum, m2);
      float inv = 1.0f / sum;
#pragma unroll
      for (int nt = 0; nt < 4; ++nt) s[mt][nt][i] *= inv;
    }
#pragma unroll
  for (int mt = 0; mt < 4; ++mt)
#pragma unroll
    for (int nt = 0; nt < 4; ++nt)
#pragma unroll
      for (int i = 0; i < 4; ++i) {
        int r = mt * 16 + g * 4 + i, j = nt * 16 + c;
        Pl[w][r * 72 + j] = f2bf(s[mt][nt][i]);
      }
  __syncthreads();
  f32x4 o[4][2] = {};
#pragma unroll
  for (int kk = 0; kk < 2; ++kk) {
    bf16x8 vb[2];
#pragma unroll
    for (int n2 = 0; n2 < 2; ++n2)
      vb[n2] = *(const bf16x8*)&Vt[w][(n2 * 16 + c) * 72 + kk * 32 + g * 8];
#pragma unroll
    for (int mt = 0; mt < 4; ++mt) {
      bf16x8 pa = *(const bf16x8*)&Pl[w][(mt * 16 + c) * 72 + kk * 32 + g * 8];
#pragma unroll
      for (int n2 = 0; n2 < 2; ++n2)
        o[mt][n2] = __builtin_amdgcn_mfma_f32_16x16x32_bf16(pa, vb[n2], o[mt][n2], 0, 0, 0);
    }
  }
#pragma unroll
  for (int mt = 0; mt < 4; ++mt)
#pragma unroll
    for (int n2 = 0; n2 < 2; ++n2)
#pragma unroll
      for (int i = 0; i < 4; ++i) {
        int r = mt * 16 + g * 4 + i;
        if (r < 49) {
          int d = n2 * 16 + c;
          ao[((size_t)win * 49 + r) * 1024 + h * 32 + d] = f2bf(o[mt][n2][i]);
        }
      }
}

// ---------------- launch ----------------
extern "C" void kernel_launch(void* const* d_in, const int* in_sizes, int n_in,
                              void* d_out, int out_size, void* d_ws, size_t ws_size,
                              hipStream_t stream) {
  (void)in_sizes; (void)n_in; (void)out_size; (void)ws_size;
  const float* x = (const float*)d_in[0];
  const float* v = (const float*)d_in[1];
  const float* n1g = (const float*)d_in[3];
  const float* n1b = (const float*)d_in[4];
  const float* qkw = (const float*)d_in[5];
  const float* qkb = (const float*)d_in[6];
  const float* rpb = (const float*)d_in[7];
  const float* pjw = (const float*)d_in[8];
  const float* pjb = (const float*)d_in[9];
  const float* n2g = (const float*)d_in[10];
  const float* n2b = (const float*)d_in[11];
  const float* f1w = (const float*)d_in[12];
  const float* f1b = (const float*)d_in[13];
  const float* f2w = (const float*)d_in[14];
  const float* f2b = (const float*)d_in[15];
  char* ws = (char*)d_ws;
  // Peak workspace: ~169 MiB
  short* w_qk = (short*)(ws + 0);                    //  4.0 MB
  short* w_pj = (short*)(ws + 4194304);              //  2.0 MB
  short* w_f1 = (short*)(ws + 6291456);              //  8.0 MB
  short* w_f2 = (short*)(ws + 14680064);             //  8.0 MB
  short* xnw  = (short*)(ws + 23068672);             // 50 MB  [ln1 -> qk gemm]
  short* qkbuf= (short*)(ws + 74448896);             // 100 MB [qk gemm -> attn]
  short* aob  = (short*)(ws + 23068672);             // 50 MB  overlays xnw [attn -> proj]
  short* xn2  = (short*)(ws + 23068672);             // 50 MB  overlays aob [ln2 -> fc1]
  short* h1   = (short*)(ws + 74448896);             // 100 MB overlays qkbuf [fc1 -> fc2, per chunk]
  float* out = (float*)d_out;                        // also holds x2 (attn residual)

  cast_qkw_kernel<<<2048, 256, 0, stream>>>(qkw, w_qk);
  cast_kernel<<<1024, 256, 0, stream>>>(pjw, w_pj);
  cast_kernel<<<4096, 256, 0, stream>>>(f1w, w_f1);
  cast_kernel<<<4096, 256, 0, stream>>>(f2w, w_f2);
  ln1_permute_kernel<<<25088, 256, 0, stream>>>(x, n1g, n1b, xnw);
  gemm8<0><<<dim3(98, 8), 512, 0, stream>>>(xnw, w_qk, qkb, nullptr, qkbuf, 2048, 1024);
  attn_kernel<<<4096, 256, 0, stream>>>(qkbuf, v, rpb, aob);
  gemm8<1><<<dim3(98, 4), 512, 0, stream>>>(aob, w_pj, pjb, x, out, 1024, 1024);
  ln2_kernel<<<25088, 256, 0, stream>>>(out, n2g, n2b, xn2);
  // MLP in 2 M-chunks of 12544 rows (hidden buffer reuses dead qkbuf region)
  for (int ch = 0; ch < 2; ++ch) {
    const short* a1 = xn2 + (size_t)ch * 12544 * 1024;
    float* o2 = out + (size_t)ch * 12544 * 1024;
    gemm8<2><<<dim3(49, 16), 512, 0, stream>>>(a1, w_f1, f1b, nullptr, h1, 4096, 1024);
    gemm8<3><<<dim3(49, 4), 512, 0, stream>>>(h1, w_f2, f2b, o2, o2, 1024, 4096);
  }
}